// Round 7
// baseline (192.746 us; speedup 1.0000x reference)
//
#include <hip/hip_runtime.h>
#include <hip/hip_bf16.h>
#include <math.h>

#define B_ 2
#define N_ 4096          // H*W*D
#define BN_ 8192
#define NH_ 4
#define SPLIT_ 8         // attention K-split

using bf16x8   = __attribute__((ext_vector_type(8))) __bf16;
using f32x4    = __attribute__((ext_vector_type(4))) float;
using ushortx8 = __attribute__((ext_vector_type(8))) unsigned short;

#if __has_builtin(__builtin_amdgcn_exp2f)
#define FAST_EXP2(x) __builtin_amdgcn_exp2f(x)
#else
#define FAST_EXP2(x) __expf((x) * 0.6931471805599453f)
#endif

static __device__ __forceinline__ unsigned short f2bf(float f) {
    union { __hip_bfloat16 h; unsigned short u; } c;
    c.h = __float2bfloat16(f);
    return c.u;
}
static __device__ __forceinline__ float bf2f(unsigned short u) {
    union { __hip_bfloat16 h; unsigned short u; } c;
    c.u = u;
    return __bfloat162float(c.h);
}
// pack two f32 -> two bf16 (round-biased truncate) in one v_perm_b32
static __device__ __forceinline__ unsigned int pk2bf(float lo, float hi) {
    return __builtin_amdgcn_perm(__float_as_uint(hi) + 0x8000u,
                                 __float_as_uint(lo) + 0x8000u, 0x07060302u);
}

// ---------------------------------------------------------------------------
// Convert all six weight matrices fp32 -> bf16.
// ---------------------------------------------------------------------------
__global__ __launch_bounds__(256)
void convert_weights_kernel(const float* __restrict__ Wq, const float* __restrict__ Wk,
                            const float* __restrict__ Wv, const float* __restrict__ Wo,
                            const float* __restrict__ W1, const float* __restrict__ W2,
                            unsigned short* __restrict__ wq, unsigned short* __restrict__ wk,
                            unsigned short* __restrict__ wv, unsigned short* __restrict__ wo,
                            unsigned short* __restrict__ w1, unsigned short* __restrict__ w2) {
    const int id = blockIdx.x * 256 + threadIdx.x;
    if      (id <  16384) wq[id]          = f2bf(Wq[id]);
    else if (id <  32768) wk[id - 16384]  = f2bf(Wk[id - 16384]);
    else if (id <  49152) wv[id - 32768]  = f2bf(Wv[id - 32768]);
    else if (id <  65536) wo[id - 49152]  = f2bf(Wo[id - 49152]);
    else if (id < 131072) w1[id - 65536]  = f2bf(W1[id - 65536]);
    else                  w2[id - 131072] = f2bf(W2[id - 131072]);
}

// ---------------------------------------------------------------------------
// LayerNorm + transpose (enc & dec merged): fp32 [B,C,N] -> bf16 [B*N, C].
// Grid (N/32, B, 2): z=0 -> enc, z=1 -> dec.
// ---------------------------------------------------------------------------
__global__ __launch_bounds__(256)
void ln_transpose_kernel(const float* __restrict__ enc, const float* __restrict__ dec,
                         const float* __restrict__ g_enc, const float* __restrict__ b_enc,
                         const float* __restrict__ g_dec, const float* __restrict__ b_dec,
                         unsigned short* __restrict__ enc_out,
                         unsigned short* __restrict__ dec_out) {
    __shared__ float tile[128][33];
    __shared__ float mu_s[32], inv_s[32];
    const int z  = blockIdx.z;
    const float* in     = z ? dec   : enc;
    const float* gamma  = z ? g_dec : g_enc;
    const float* beta   = z ? b_dec : b_enc;
    unsigned short* outb = z ? dec_out : enc_out;
    const int b  = blockIdx.y;
    const int n0 = blockIdx.x * 32;
    const int t  = threadIdx.x;
    const float* inb = in + (size_t)b * 128 * N_;

    {
        const int col = t & 31;
        const int r0  = t >> 5;
        for (int j = 0; j < 16; ++j) {
            const int r = r0 + 8 * j;
            tile[r][col] = inb[(size_t)r * N_ + n0 + col];
        }
    }
    __syncthreads();
    {
        const int tok = t >> 3;
        const int ln  = t & 7;
        float s = 0.f, ss = 0.f;
        for (int c = ln; c < 128; c += 8) {
            const float x = tile[c][tok];
            s += x; ss += x * x;
        }
        for (int m = 1; m < 8; m <<= 1) {
            s  += __shfl_xor(s, m);
            ss += __shfl_xor(ss, m);
        }
        if (ln == 0) {
            const float mu  = s * (1.f / 128.f);
            const float var = ss * (1.f / 128.f) - mu * mu;
            mu_s[tok]  = mu;
            inv_s[tok] = rsqrtf(var + 1e-5f);
        }
    }
    __syncthreads();
    const size_t obase = ((size_t)b * N_ + n0) * 128;
    for (int j = 0; j < 16; ++j) {
        const int f  = t + 256 * j;
        const int tk = f >> 7;
        const int c  = f & 127;
        const float x = tile[c][tk];
        outb[obase + f] = f2bf((x - mu_s[tk]) * inv_s[tk] * gamma[c] + beta[c]);
    }
}

// ---------------------------------------------------------------------------
// QKV projection, bf16 MFMA, no LDS. Q is pre-scaled by (1/sqrt(d))*log2(e)
// so attention can use raw exp2. V written pre-transposed [bh, 32, n].
// ---------------------------------------------------------------------------
__global__ __launch_bounds__(128)
void qkv_gemm_kernel(const unsigned short* __restrict__ decb,
                     const unsigned short* __restrict__ encb,
                     const unsigned short* __restrict__ wq,
                     const unsigned short* __restrict__ wk,
                     const unsigned short* __restrict__ wv,
                     const float* __restrict__ bq, const float* __restrict__ bk,
                     const float* __restrict__ bv,
                     unsigned short* __restrict__ Qh, unsigned short* __restrict__ Kh,
                     unsigned short* __restrict__ Vt) {
    const int z = blockIdx.y;
    const int t = threadIdx.x;
    const int wvx = t >> 6, lane = t & 63;
    const int l15 = lane & 15, quad = lane >> 4;
    const int m0 = blockIdx.x * 32 + wvx * 16;
    const unsigned short* X    = (z == 0) ? decb : encb;
    const unsigned short* Wb   = (z == 0) ? wq : (z == 1) ? wk : wv;
    const float*          bias = (z == 0) ? bq : (z == 1) ? bk : bv;

    bf16x8 af[4];
    #pragma unroll
    for (int kk = 0; kk < 4; ++kk)
        af[kk] = *(const bf16x8*)(X + (size_t)(m0 + l15) * 128 + kk * 32 + quad * 8);

    f32x4 acc[8];
    #pragma unroll
    for (int nb = 0; nb < 8; ++nb) {
        f32x4 a = {0.f, 0.f, 0.f, 0.f};
        #pragma unroll
        for (int kk = 0; kk < 4; ++kk) {
            const bf16x8 wf = *(const bf16x8*)(Wb + (size_t)(nb * 16 + l15) * 128 + kk * 32 + quad * 8);
            a = __builtin_amdgcn_mfma_f32_16x16x32_bf16(af[kk], wf, a, 0, 0, 0);
        }
        acc[nb] = a;
    }

    const float qsc = 0.17677669529663687f * 1.4426950408889634f;  // 1/sqrt(32)*log2e
    const int b   = m0 >> 12;
    const int nb0 = (m0 & 4095) + quad * 4;
    #pragma unroll
    for (int nb = 0; nb < 8; ++nb) {
        const int col = nb * 16 + l15;
        const int h = col >> 5, d = col & 31;
        const float bz = bias[col];
        if (z == 2) {
            ushort4 pk;
            pk.x = f2bf(acc[nb][0] + bz);
            pk.y = f2bf(acc[nb][1] + bz);
            pk.z = f2bf(acc[nb][2] + bz);
            pk.w = f2bf(acc[nb][3] + bz);
            *(ushort4*)(Vt + ((size_t)(b * NH_ + h) * 32 + d) * N_ + nb0) = pk;
        } else {
            unsigned short* dst = (z == 0) ? Qh : Kh;
            const float sc = (z == 0) ? qsc : 1.f;
            #pragma unroll
            for (int r = 0; r < 4; ++r) {
                const int n = nb0 + r;
                dst[((size_t)(b * NH_ + h) * N_ + n) * 32 + d] = f2bf((acc[nb][r] + bz) * sc);
            }
        }
    }
}

// ---------------------------------------------------------------------------
// Split-K MFMA flash attention v6: 32 q per wave (2 Q-frags), 128 q/block,
// 2048 blocks for TLP. XCD-affine 1-D grid: gid%8 == bh -> per-XCD K/V
// residency (512 KB in 4 MB L2). Max-free base-2 softmax; K prefetched one
// chunk ahead; sP wave-private (no barriers).
// ---------------------------------------------------------------------------
__global__ __launch_bounds__(256)
void attn_kernel6(const unsigned short* __restrict__ Qh,
                  const unsigned short* __restrict__ Kh,
                  const unsigned short* __restrict__ Vt,
                  unsigned short* __restrict__ Op,
                  unsigned short* __restrict__ lp) {
    __shared__ alignas(16) unsigned short sP[4][32][72];  // 18.4 KB

    const int gid   = blockIdx.x;
    const int combo = gid & 63;         // s*8 + bh
    const int qblk  = gid >> 6;         // 0..31
    const int bh    = combo & 7;
    const int s     = combo >> 3;
    const int t  = threadIdx.x;
    const int wvx = t >> 6, lane = t & 63;
    const int l15 = lane & 15, quad = lane >> 4;
    const int qw = qblk * 128 + wvx * 32;     // wave's q base (32 rows)
    const size_t hbse = (size_t)bh * N_ * 32;

    bf16x8 qf[2];
    #pragma unroll
    for (int f = 0; f < 2; ++f)
        qf[f] = *(const bf16x8*)(Qh + hbse + (size_t)(qw + f * 16 + l15) * 32 + quad * 8);

    const unsigned short* Kp = Kh + hbse;
    const unsigned short* Vp = Vt + (size_t)bh * 32 * N_;

    f32x4 o0[2], o1[2];
    float l[2];
    #pragma unroll
    for (int f = 0; f < 2; ++f) {
        o0[f] = f32x4{0.f, 0.f, 0.f, 0.f};
        o1[f] = f32x4{0.f, 0.f, 0.f, 0.f};
        l[f] = 0.f;
    }
    const f32x4 zero = {0.f, 0.f, 0.f, 0.f};

    const int kbeg = s * (N_ / SPLIT_);
    const int kend = kbeg + (N_ / SPLIT_);

    bf16x8 kf[4];
    #pragma unroll
    for (int c = 0; c < 4; ++c)
        kf[c] = *(const bf16x8*)(Kp + (size_t)(kbeg + c * 16 + l15) * 32 + quad * 8);

    for (int k0 = kbeg; k0 < kend; k0 += 64) {
        bf16x8 va[2], vb[2];
        #pragma unroll
        for (int s2 = 0; s2 < 2; ++s2) {
            va[s2] = *(const bf16x8*)(Vp + (size_t)l15 * N_        + k0 + s2 * 32 + quad * 8);
            vb[s2] = *(const bf16x8*)(Vp + (size_t)(16 + l15) * N_ + k0 + s2 * 32 + quad * 8);
        }
        const int kn = (k0 + 64 < kend) ? (k0 + 64) : kbeg;
        bf16x8 kfn[4];
        #pragma unroll
        for (int c = 0; c < 4; ++c)
            kfn[c] = *(const bf16x8*)(Kp + (size_t)(kn + c * 16 + l15) * 32 + quad * 8);

        #pragma unroll
        for (int f = 0; f < 2; ++f) {
            #pragma unroll
            for (int c = 0; c < 4; ++c) {
                const f32x4 sv = __builtin_amdgcn_mfma_f32_16x16x32_bf16(kf[c], qf[f], zero, 0, 0, 0);
                const float p0 = FAST_EXP2(sv[0]);
                const float p1 = FAST_EXP2(sv[1]);
                const float p2 = FAST_EXP2(sv[2]);
                const float p3 = FAST_EXP2(sv[3]);
                l[f] += (p0 + p1) + (p2 + p3);
                uint2 pk;
                pk.x = pk2bf(p0, p1);
                pk.y = pk2bf(p2, p3);
                *(uint2*)&sP[wvx][f * 16 + l15][c * 16 + quad * 4] = pk;
            }
        }
        #pragma unroll
        for (int f = 0; f < 2; ++f) {
            #pragma unroll
            for (int s2 = 0; s2 < 2; ++s2) {
                const bf16x8 pf = *(const bf16x8*)&sP[wvx][f * 16 + l15][s2 * 32 + quad * 8];
                o0[f] = __builtin_amdgcn_mfma_f32_16x16x32_bf16(va[s2], pf, o0[f], 0, 0, 0);
                o1[f] = __builtin_amdgcn_mfma_f32_16x16x32_bf16(vb[s2], pf, o1[f], 0, 0, 0);
            }
        }
        #pragma unroll
        for (int c = 0; c < 4; ++c) kf[c] = kfn[c];
    }

    #pragma unroll
    for (int f = 0; f < 2; ++f) {
        float lf = l[f];
        lf += __shfl_xor(lf, 16);
        lf += __shfl_xor(lf, 32);
        const int tok = qw + f * 16 + l15;
        const size_t ob = ((size_t)(s * 8 + bh) * N_ + tok) * 32;
        uint2 w0, w1v;
        w0.x  = pk2bf(o0[f][0], o0[f][1]); w0.y  = pk2bf(o0[f][2], o0[f][3]);
        w1v.x = pk2bf(o1[f][0], o1[f][1]); w1v.y = pk2bf(o1[f][2], o1[f][3]);
        *(uint2*)&Op[ob + quad * 4]      = w0;
        *(uint2*)&Op[ob + 16 + quad * 4] = w1v;
        if (quad == 0)
            lp[(size_t)(s * 8 + bh) * N_ + tok] = f2bf(lf);
    }
}

// ---------------------------------------------------------------------------
// Fused tail: combine + Wo + residual + LN + FFN1(gelu) + FFN2 + residual,
// written directly to [B,128,N] fp32 output. Block = 256 thr = 4 waves
// (2 token-tiles "pair" x 2 halves "kh"), 32 tokens per block, grid BN/32.
// out1 lives in registers; hb and mid pass through LDS only.
// ---------------------------------------------------------------------------
__global__ __launch_bounds__(256)
void fused_tail_kernel(const unsigned short* __restrict__ Op,
                       const unsigned short* __restrict__ lp,
                       const unsigned short* __restrict__ wo,
                       const float* __restrict__ bo,
                       const unsigned short* __restrict__ decb,
                       const float* __restrict__ g, const float* __restrict__ be,
                       const unsigned short* __restrict__ w1,
                       const float* __restrict__ b1,
                       const unsigned short* __restrict__ w2,
                       const float* __restrict__ b2,
                       float* __restrict__ out) {
    __shared__ alignas(16) float sred[2][64][32];              // 16 KB
    __shared__ alignas(16) unsigned short hb_lds[32][136];     // 8.7 KB
    __shared__ alignas(16) unsigned short smid[2][16][536];    // 34.3 KB
    const int t = threadIdx.x;
    const int wvx = t >> 6, lane = t & 63;
    const int pair = wvx >> 1, kh = wvx & 1;
    const int l15 = lane & 15, quad = lane >> 4;
    const int m0 = blockIdx.x * 32 + pair * 16;

    // ---- combine folded into A-frag build: chans [kh*64, kh*64+64) = heads kh*2, kh*2+1
    const int tokA = m0 + l15;
    const int bA = tokA >> 12, nA = tokA & 4095;
    bf16x8 af[2];
    #pragma unroll
    for (int kkl = 0; kkl < 2; ++kkl) {
        const int bhh = bA * NH_ + kh * 2 + kkl;
        f32x4 sa = {0.f, 0.f, 0.f, 0.f}, sb = {0.f, 0.f, 0.f, 0.f};
        float lt = 0.f;
        #pragma unroll
        for (int s = 0; s < SPLIT_; ++s) {
            const size_t base = ((size_t)(s * 8 + bhh) * N_ + nA) * 32 + quad * 8;
            const ushortx8 u = *(const ushortx8*)&Op[base];
            sa[0] += bf2f(u[0]); sa[1] += bf2f(u[1]);
            sa[2] += bf2f(u[2]); sa[3] += bf2f(u[3]);
            sb[0] += bf2f(u[4]); sb[1] += bf2f(u[5]);
            sb[2] += bf2f(u[6]); sb[3] += bf2f(u[7]);
            lt += bf2f(lp[(size_t)(s * 8 + bhh) * N_ + nA]);
        }
        const float inv = 1.f / lt;
        union { uint4 u; bf16x8 v; } cvt;
        cvt.u.x = pk2bf(sa[0] * inv, sa[1] * inv);
        cvt.u.y = pk2bf(sa[2] * inv, sa[3] * inv);
        cvt.u.z = pk2bf(sb[0] * inv, sb[1] * inv);
        cvt.u.w = pk2bf(sb[2] * inv, sb[3] * inv);
        af[kkl] = cvt.v;
    }

    // ---- Wo GEMM (half-K per wave)
    float v[8][4];
    #pragma unroll
    for (int nb = 0; nb < 8; ++nb) {
        f32x4 a = {0.f, 0.f, 0.f, 0.f};
        #pragma unroll
        for (int kkl = 0; kkl < 2; ++kkl) {
            const bf16x8 wf = *(const bf16x8*)(wo + (size_t)(nb * 16 + l15) * 128
                                               + (kh * 2 + kkl) * 32 + quad * 8);
            a = __builtin_amdgcn_mfma_f32_16x16x32_bf16(af[kkl], wf, a, 0, 0, 0);
        }
        #pragma unroll
        for (int r = 0; r < 4; ++r) v[nb][r] = a[r];
    }
    if (kh == 1) {
        #pragma unroll
        for (int nb = 0; nb < 8; ++nb)
            *(f32x4*)&sred[pair][lane][nb * 4] = *(f32x4*)&v[nb][0];
    }
    __syncthreads();

    // ---- residual + LN (kh==0 waves); out1 stays in v[][]; hb -> LDS
    if (kh == 0) {
        #pragma unroll
        for (int nb = 0; nb < 8; ++nb) {
            const f32x4 p = *(const f32x4*)&sred[pair][lane][nb * 4];
            const int col = nb * 16 + l15;
            const float bz = bo[col];
            #pragma unroll
            for (int r = 0; r < 4; ++r) {
                const int tok = m0 + quad * 4 + r;
                v[nb][r] += p[r] + bz + bf2f(decb[(size_t)tok * 128 + col]);
            }
        }
        float mu[4], inv[4];
        #pragma unroll
        for (int r = 0; r < 4; ++r) {
            float s = 0.f, ss = 0.f;
            #pragma unroll
            for (int nb = 0; nb < 8; ++nb) { s += v[nb][r]; ss += v[nb][r] * v[nb][r]; }
            for (int m = 1; m < 16; m <<= 1) {
                s  += __shfl_xor(s, m);
                ss += __shfl_xor(ss, m);
            }
            mu[r] = s * (1.f / 128.f);
            inv[r] = rsqrtf(ss * (1.f / 128.f) - mu[r] * mu[r] + 1e-5f);
        }
        #pragma unroll
        for (int nb = 0; nb < 8; ++nb) {
            const int col = nb * 16 + l15;
            const float gg = g[col], bb2 = be[col];
            #pragma unroll
            for (int r = 0; r < 4; ++r)
                hb_lds[pair * 16 + quad * 4 + r][col] =
                    f2bf((v[nb][r] - mu[r]) * inv[r] * gg + bb2);
        }
    }
    __syncthreads();

    // ---- FFN1: wave covers cols [kh*256, kh*256+256) for its pair's tokens
    bf16x8 hf[4];
    #pragma unroll
    for (int kk = 0; kk < 4; ++kk)
        hf[kk] = *(const bf16x8*)&hb_lds[pair * 16 + l15][kk * 32 + quad * 8];
    #pragma unroll
    for (int nb = 0; nb < 16; ++nb) {
        const int col = kh * 256 + nb * 16 + l15;
        f32x4 a = {0.f, 0.f, 0.f, 0.f};
        #pragma unroll
        for (int kk = 0; kk < 4; ++kk) {
            const bf16x8 wf = *(const bf16x8*)(w1 + (size_t)col * 128 + kk * 32 + quad * 8);
            a = __builtin_amdgcn_mfma_f32_16x16x32_bf16(hf[kk], wf, a, 0, 0, 0);
        }
        const float bz = b1[col];
        #pragma unroll
        for (int r = 0; r < 4; ++r) {
            float x = a[r] + bz;
            x = 0.5f * x * (1.f + erff(x * 0.70710678118f));
            smid[pair][quad * 4 + r][col] = f2bf(x);
        }
    }
    __syncthreads();

    // ---- FFN2: wave accumulates its K-half [kh*256, kh*256+256)
    f32x4 acc[8];
    #pragma unroll
    for (int nb = 0; nb < 8; ++nb) acc[nb] = f32x4{0.f, 0.f, 0.f, 0.f};
    #pragma unroll
    for (int kk = 0; kk < 8; ++kk) {
        const bf16x8 af2 = *(const bf16x8*)&smid[pair][l15][kh * 256 + kk * 32 + quad * 8];
        #pragma unroll
        for (int nb = 0; nb < 8; ++nb) {
            const bf16x8 wf = *(const bf16x8*)(w2 + (size_t)(nb * 16 + l15) * 512
                                               + kh * 256 + kk * 32 + quad * 8);
            acc[nb] = __builtin_amdgcn_mfma_f32_16x16x32_bf16(af2, wf, acc[nb], 0, 0, 0);
        }
    }
    if (kh == 1) {
        #pragma unroll
        for (int nb = 0; nb < 8; ++nb)
            *(f32x4*)&sred[pair][lane][nb * 4] = acc[nb];
    }
    __syncthreads();
    if (kh == 0) {
        const int b = m0 >> 12;
        const int nb0 = (m0 & 4095) + quad * 4;
        #pragma unroll
        for (int nb = 0; nb < 8; ++nb) {
            const f32x4 p = *(const f32x4*)&sred[pair][lane][nb * 4];
            const int col = nb * 16 + l15;
            const float bz = b2[col];
            f32x4 res;
            #pragma unroll
            for (int r = 0; r < 4; ++r)
                res[r] = acc[nb][r] + p[r] + bz + v[nb][r];   // v = out1 (regs)
            *(f32x4*)&out[((size_t)(b * 128 + col)) * N_ + nb0] = res;
        }
    }
}

// ---------------------------------------------------------------------------
extern "C" void kernel_launch(void* const* d_in, const int* in_sizes, int n_in,
                              void* d_out, int out_size, void* d_ws, size_t ws_size,
                              hipStream_t stream) {
    const float* enc   = (const float*)d_in[0];
    const float* dec   = (const float*)d_in[1];
    const float* Wq    = (const float*)d_in[2];
    const float* bq    = (const float*)d_in[3];
    const float* Wk    = (const float*)d_in[4];
    const float* bk    = (const float*)d_in[5];
    const float* Wv    = (const float*)d_in[6];
    const float* bv    = (const float*)d_in[7];
    const float* Wo    = (const float*)d_in[8];
    const float* bo    = (const float*)d_in[9];
    const float* g_enc = (const float*)d_in[10];
    const float* b_enc = (const float*)d_in[11];
    const float* g_dec = (const float*)d_in[12];
    const float* b_dec = (const float*)d_in[13];
    const float* g_out = (const float*)d_in[14];
    const float* b_out = (const float*)d_in[15];
    const float* W1    = (const float*)d_in[16];
    const float* b1    = (const float*)d_in[17];
    const float* W2    = (const float*)d_in[18];
    const float* b2    = (const float*)d_in[19];
    float* out = (float*)d_out;
    char*  W   = (char*)d_ws;

    // workspace layout (27 MB, identical footprint to R6 which passed)
    unsigned short* wqb = (unsigned short*)(W);
    unsigned short* wkb = wqb + 16384;
    unsigned short* wvb = wkb + 16384;
    unsigned short* wob = wvb + 16384;
    unsigned short* w1b = wob + 16384;
    unsigned short* w2b = w1b + 65536;                                  // ends 384 KB
    unsigned short* enc_lnb = (unsigned short*)(W + (512ull  << 10));   // [0.5, 2.5) MB
    unsigned short* dec_lnb = (unsigned short*)(W + (2560ull << 10));   // [2.5, 4.5)
    unsigned short* Qh      = (unsigned short*)(W + (4608ull << 10));   // [4.5, 6.5)
    unsigned short* Kh      = (unsigned short*)(W + (6656ull << 10));   // [6.5, 8.5)
    unsigned short* Vt      = (unsigned short*)(W + (8704ull << 10));   // [8.5, 10.5)
    unsigned short* Op      = (unsigned short*)(W + (10752ull << 10));  // 16 MB (SPLIT=8)
    unsigned short* lpb     = (unsigned short*)(W + (27136ull << 10));  // [26.5, 27)

    convert_weights_kernel<<<768, 256, 0, stream>>>(Wq, Wk, Wv, Wo, W1, W2,
                                                    wqb, wkb, wvb, wob, w1b, w2b);

    ln_transpose_kernel<<<dim3(N_ / 32, B_, 2), 256, 0, stream>>>(
        enc, dec, g_enc, b_enc, g_dec, b_dec, enc_lnb, dec_lnb);

    qkv_gemm_kernel<<<dim3(BN_ / 32, 3), 128, 0, stream>>>(
        dec_lnb, enc_lnb, wqb, wkb, wvb, bq, bk, bv, Qh, Kh, Vt);

    // 2048 blocks, XCD-affine: gid = qblk*64 + (s*8+bh) -> gid%8 == bh
    attn_kernel6<<<2048, 256, 0, stream>>>(Qh, Kh, Vt, Op, lpb);

    fused_tail_kernel<<<BN_ / 32, 256, 0, stream>>>(Op, lpb, wob, bo, dec_lnb,
                                                    g_out, b_out, w1b, b1, w2b, b2, out);
}

// Round 8
// 174.671 us; speedup vs baseline: 1.1035x; 1.1035x over previous
//
#include <hip/hip_runtime.h>
#include <hip/hip_bf16.h>
#include <math.h>

#define B_ 2
#define N_ 4096          // H*W*D
#define BN_ 8192
#define NH_ 4
#define SPLIT_ 8         // attention K-split

using bf16x8   = __attribute__((ext_vector_type(8))) __bf16;
using f32x4    = __attribute__((ext_vector_type(4))) float;
using ushortx8 = __attribute__((ext_vector_type(8))) unsigned short;

#if __has_builtin(__builtin_amdgcn_exp2f)
#define FAST_EXP2(x) __builtin_amdgcn_exp2f(x)
#else
#define FAST_EXP2(x) __expf((x) * 0.6931471805599453f)
#endif

static __device__ __forceinline__ unsigned short f2bf(float f) {
    union { __hip_bfloat16 h; unsigned short u; } c;
    c.h = __float2bfloat16(f);
    return c.u;
}
static __device__ __forceinline__ float bf2f(unsigned short u) {
    union { __hip_bfloat16 h; unsigned short u; } c;
    c.u = u;
    return __bfloat162float(c.h);
}
// pack two f32 -> two bf16 (round-biased truncate) in one v_perm_b32
static __device__ __forceinline__ unsigned int pk2bf(float lo, float hi) {
    return __builtin_amdgcn_perm(__float_as_uint(hi) + 0x8000u,
                                 __float_as_uint(lo) + 0x8000u, 0x07060302u);
}

// ---------------------------------------------------------------------------
// Fused pre-pass: blocks 0..767 convert weights fp32->bf16; blocks 768..1279
// do LayerNorm+transpose of enc/dec (fp32 [B,C,N] -> bf16 [B*N, C]).
// ---------------------------------------------------------------------------
__global__ __launch_bounds__(256)
void fused_pre_kernel(const float* __restrict__ Wq, const float* __restrict__ Wk,
                      const float* __restrict__ Wv, const float* __restrict__ Wo,
                      const float* __restrict__ W1, const float* __restrict__ W2,
                      unsigned short* __restrict__ wq, unsigned short* __restrict__ wk,
                      unsigned short* __restrict__ wv, unsigned short* __restrict__ wo,
                      unsigned short* __restrict__ w1, unsigned short* __restrict__ w2,
                      const float* __restrict__ enc, const float* __restrict__ dec,
                      const float* __restrict__ g_enc, const float* __restrict__ b_enc,
                      const float* __restrict__ g_dec, const float* __restrict__ b_dec,
                      unsigned short* __restrict__ enc_out,
                      unsigned short* __restrict__ dec_out) {
    __shared__ float tile[128][33];
    __shared__ float mu_s[32], inv_s[32];
    const int t = threadIdx.x;
    if (blockIdx.x < 768) {
        const int id = blockIdx.x * 256 + t;
        if      (id <  16384) wq[id]          = f2bf(Wq[id]);
        else if (id <  32768) wk[id - 16384]  = f2bf(Wk[id - 16384]);
        else if (id <  49152) wv[id - 32768]  = f2bf(Wv[id - 32768]);
        else if (id <  65536) wo[id - 49152]  = f2bf(Wo[id - 49152]);
        else if (id < 131072) w1[id - 65536]  = f2bf(W1[id - 65536]);
        else                  w2[id - 131072] = f2bf(W2[id - 131072]);
        return;
    }
    const int idx = blockIdx.x - 768;          // 0..511
    const int x = idx & 127;                   // n-tile
    const int b = (idx >> 7) & 1;
    const int z = idx >> 8;                    // 0 enc, 1 dec
    const float* in     = z ? dec   : enc;
    const float* gamma  = z ? g_dec : g_enc;
    const float* beta   = z ? b_dec : b_enc;
    unsigned short* outb = z ? dec_out : enc_out;
    const int n0 = x * 32;
    const float* inb = in + (size_t)b * 128 * N_;

    {
        const int col = t & 31;
        const int r0  = t >> 5;
        for (int j = 0; j < 16; ++j) {
            const int r = r0 + 8 * j;
            tile[r][col] = inb[(size_t)r * N_ + n0 + col];
        }
    }
    __syncthreads();
    {
        const int tok = t >> 3;
        const int ln  = t & 7;
        float s = 0.f, ss = 0.f;
        for (int c = ln; c < 128; c += 8) {
            const float x2 = tile[c][tok];
            s += x2; ss += x2 * x2;
        }
        for (int m = 1; m < 8; m <<= 1) {
            s  += __shfl_xor(s, m);
            ss += __shfl_xor(ss, m);
        }
        if (ln == 0) {
            const float mu  = s * (1.f / 128.f);
            const float var = ss * (1.f / 128.f) - mu * mu;
            mu_s[tok]  = mu;
            inv_s[tok] = rsqrtf(var + 1e-5f);
        }
    }
    __syncthreads();
    const size_t obase = ((size_t)b * N_ + n0) * 128;
    for (int j = 0; j < 16; ++j) {
        const int f  = t + 256 * j;
        const int tk = f >> 7;
        const int c  = f & 127;
        const float x2 = tile[c][tk];
        outb[obase + f] = f2bf((x2 - mu_s[tk]) * inv_s[tk] * gamma[c] + beta[c]);
    }
}

// ---------------------------------------------------------------------------
// QKV projection, bf16 MFMA, no LDS. Q is pre-scaled by (1/sqrt(d))*log2(e)
// so attention can use raw exp2. V written pre-transposed [bh, 32, n].
// ---------------------------------------------------------------------------
__global__ __launch_bounds__(128)
void qkv_gemm_kernel(const unsigned short* __restrict__ decb,
                     const unsigned short* __restrict__ encb,
                     const unsigned short* __restrict__ wq,
                     const unsigned short* __restrict__ wk,
                     const unsigned short* __restrict__ wv,
                     const float* __restrict__ bq, const float* __restrict__ bk,
                     const float* __restrict__ bv,
                     unsigned short* __restrict__ Qh, unsigned short* __restrict__ Kh,
                     unsigned short* __restrict__ Vt) {
    const int z = blockIdx.y;
    const int t = threadIdx.x;
    const int wvx = t >> 6, lane = t & 63;
    const int l15 = lane & 15, quad = lane >> 4;
    const int m0 = blockIdx.x * 32 + wvx * 16;
    const unsigned short* X    = (z == 0) ? decb : encb;
    const unsigned short* Wb   = (z == 0) ? wq : (z == 1) ? wk : wv;
    const float*          bias = (z == 0) ? bq : (z == 1) ? bk : bv;

    bf16x8 af[4];
    #pragma unroll
    for (int kk = 0; kk < 4; ++kk)
        af[kk] = *(const bf16x8*)(X + (size_t)(m0 + l15) * 128 + kk * 32 + quad * 8);

    f32x4 acc[8];
    #pragma unroll
    for (int nb = 0; nb < 8; ++nb) {
        f32x4 a = {0.f, 0.f, 0.f, 0.f};
        #pragma unroll
        for (int kk = 0; kk < 4; ++kk) {
            const bf16x8 wf = *(const bf16x8*)(Wb + (size_t)(nb * 16 + l15) * 128 + kk * 32 + quad * 8);
            a = __builtin_amdgcn_mfma_f32_16x16x32_bf16(af[kk], wf, a, 0, 0, 0);
        }
        acc[nb] = a;
    }

    const float qsc = 0.17677669529663687f * 1.4426950408889634f;  // 1/sqrt(32)*log2e
    const int b   = m0 >> 12;
    const int nb0 = (m0 & 4095) + quad * 4;
    #pragma unroll
    for (int nb = 0; nb < 8; ++nb) {
        const int col = nb * 16 + l15;
        const int h = col >> 5, d = col & 31;
        const float bz = bias[col];
        if (z == 2) {
            ushort4 pk;
            pk.x = f2bf(acc[nb][0] + bz);
            pk.y = f2bf(acc[nb][1] + bz);
            pk.z = f2bf(acc[nb][2] + bz);
            pk.w = f2bf(acc[nb][3] + bz);
            *(ushort4*)(Vt + ((size_t)(b * NH_ + h) * 32 + d) * N_ + nb0) = pk;
        } else {
            unsigned short* dst = (z == 0) ? Qh : Kh;
            const float sc = (z == 0) ? qsc : 1.f;
            #pragma unroll
            for (int r = 0; r < 4; ++r) {
                const int n = nb0 + r;
                dst[((size_t)(b * NH_ + h) * N_ + n) * 32 + d] = f2bf((acc[nb][r] + bz) * sc);
            }
        }
    }
}

// ---------------------------------------------------------------------------
// Split-K MFMA flash attention (R6-proven config): 64 q per wave (4 Q-frags),
// 256 q/block, 1024 blocks. XCD-affine 1-D grid: gid%8 == bh -> per-XCD K/V
// L2 residency. Max-free base-2 softmax; K prefetched one chunk ahead;
// sP wave-private (no barriers).
// ---------------------------------------------------------------------------
__global__ __launch_bounds__(256)
void attn_kernel5(const unsigned short* __restrict__ Qh,
                  const unsigned short* __restrict__ Kh,
                  const unsigned short* __restrict__ Vt,
                  unsigned short* __restrict__ Op,
                  unsigned short* __restrict__ lp) {
    __shared__ alignas(16) unsigned short sP[4][64][72];  // 36.9 KB

    const int gid   = blockIdx.x;
    const int combo = gid & 63;         // s*8 + bh
    const int qblk  = gid >> 6;         // 0..15
    const int bh    = combo & 7;
    const int s     = combo >> 3;
    const int t  = threadIdx.x;
    const int wvx = t >> 6, lane = t & 63;
    const int l15 = lane & 15, quad = lane >> 4;
    const int qw = qblk * 256 + wvx * 64;
    const size_t hbse = (size_t)bh * N_ * 32;

    bf16x8 qf[4];
    #pragma unroll
    for (int f = 0; f < 4; ++f)
        qf[f] = *(const bf16x8*)(Qh + hbse + (size_t)(qw + f * 16 + l15) * 32 + quad * 8);

    const unsigned short* Kp = Kh + hbse;
    const unsigned short* Vp = Vt + (size_t)bh * 32 * N_;

    f32x4 o0[4], o1[4];
    float l[4];
    #pragma unroll
    for (int f = 0; f < 4; ++f) {
        o0[f] = f32x4{0.f, 0.f, 0.f, 0.f};
        o1[f] = f32x4{0.f, 0.f, 0.f, 0.f};
        l[f] = 0.f;
    }
    const f32x4 zero = {0.f, 0.f, 0.f, 0.f};

    const int kbeg = s * (N_ / SPLIT_);
    const int kend = kbeg + (N_ / SPLIT_);

    bf16x8 kf[4];
    #pragma unroll
    for (int c = 0; c < 4; ++c)
        kf[c] = *(const bf16x8*)(Kp + (size_t)(kbeg + c * 16 + l15) * 32 + quad * 8);

    for (int k0 = kbeg; k0 < kend; k0 += 64) {
        bf16x8 va[2], vb[2];
        #pragma unroll
        for (int s2 = 0; s2 < 2; ++s2) {
            va[s2] = *(const bf16x8*)(Vp + (size_t)l15 * N_        + k0 + s2 * 32 + quad * 8);
            vb[s2] = *(const bf16x8*)(Vp + (size_t)(16 + l15) * N_ + k0 + s2 * 32 + quad * 8);
        }
        const int kn = (k0 + 64 < kend) ? (k0 + 64) : kbeg;
        bf16x8 kfn[4];
        #pragma unroll
        for (int c = 0; c < 4; ++c)
            kfn[c] = *(const bf16x8*)(Kp + (size_t)(kn + c * 16 + l15) * 32 + quad * 8);

        #pragma unroll
        for (int f = 0; f < 4; ++f) {
            #pragma unroll
            for (int c = 0; c < 4; ++c) {
                const f32x4 sv = __builtin_amdgcn_mfma_f32_16x16x32_bf16(kf[c], qf[f], zero, 0, 0, 0);
                const float p0 = FAST_EXP2(sv[0]);
                const float p1 = FAST_EXP2(sv[1]);
                const float p2 = FAST_EXP2(sv[2]);
                const float p3 = FAST_EXP2(sv[3]);
                l[f] += (p0 + p1) + (p2 + p3);
                uint2 pk;
                pk.x = pk2bf(p0, p1);
                pk.y = pk2bf(p2, p3);
                *(uint2*)&sP[wvx][f * 16 + l15][c * 16 + quad * 4] = pk;
            }
        }
        #pragma unroll
        for (int f = 0; f < 4; ++f) {
            #pragma unroll
            for (int s2 = 0; s2 < 2; ++s2) {
                const bf16x8 pf = *(const bf16x8*)&sP[wvx][f * 16 + l15][s2 * 32 + quad * 8];
                o0[f] = __builtin_amdgcn_mfma_f32_16x16x32_bf16(va[s2], pf, o0[f], 0, 0, 0);
                o1[f] = __builtin_amdgcn_mfma_f32_16x16x32_bf16(vb[s2], pf, o1[f], 0, 0, 0);
            }
        }
        #pragma unroll
        for (int c = 0; c < 4; ++c) kf[c] = kfn[c];
    }

    #pragma unroll
    for (int f = 0; f < 4; ++f) {
        float lf = l[f];
        lf += __shfl_xor(lf, 16);
        lf += __shfl_xor(lf, 32);
        const int tok = qw + f * 16 + l15;
        const size_t ob = ((size_t)(s * 8 + bh) * N_ + tok) * 32;
        uint2 w0, w1v;
        w0.x  = pk2bf(o0[f][0], o0[f][1]); w0.y  = pk2bf(o0[f][2], o0[f][3]);
        w1v.x = pk2bf(o1[f][0], o1[f][1]); w1v.y = pk2bf(o1[f][2], o1[f][3]);
        *(uint2*)&Op[ob + quad * 4]      = w0;
        *(uint2*)&Op[ob + 16 + quad * 4] = w1v;
        if (quad == 0)
            lp[(size_t)(s * 8 + bh) * N_ + tok] = f2bf(lf);
    }
}

// ---------------------------------------------------------------------------
// Fused tail v2: combine + Wo + residual + LN + FFN1(gelu) + FFN2 + residual
// -> [B,128,N] fp32. 512 blocks x 16 tokens; 4 waves = 4-way K-split in every
// GEMM phase (wave wv: head wv for combine/Wo; cols [wv*128,..) for FFN1;
// K-quarter wv for FFN2). out1 in registers; hb/mid via LDS only.
// ---------------------------------------------------------------------------
__global__ __launch_bounds__(256)
void fused_tail2_kernel(const unsigned short* __restrict__ Op,
                        const unsigned short* __restrict__ lp,
                        const unsigned short* __restrict__ wo,
                        const float* __restrict__ bo,
                        const unsigned short* __restrict__ decb,
                        const float* __restrict__ g, const float* __restrict__ be,
                        const unsigned short* __restrict__ w1,
                        const float* __restrict__ b1,
                        const unsigned short* __restrict__ w2,
                        const float* __restrict__ b2,
                        float* __restrict__ out) {
    __shared__ alignas(16) float sred[4][64][32];              // 32 KB
    __shared__ float sln[4][2][16];                            // 0.5 KB
    __shared__ alignas(16) unsigned short hb_lds[16][136];     // 4.25 KB
    __shared__ alignas(16) unsigned short smid[16][536];       // 16.75 KB
    const int t = threadIdx.x;
    const int wv = t >> 6, lane = t & 63;
    const int l15 = lane & 15, quad = lane >> 4;
    const int m0 = blockIdx.x * 16;

    // ---- combine (head wv) + Wo A-frag
    const int tokA = m0 + l15;
    const int bA = tokA >> 12, nA = tokA & 4095;
    const int bhh = bA * NH_ + wv;
    bf16x8 af;
    {
        f32x4 sa = {0.f, 0.f, 0.f, 0.f}, sb = {0.f, 0.f, 0.f, 0.f};
        float lt = 0.f;
        #pragma unroll
        for (int s = 0; s < SPLIT_; ++s) {
            const size_t base = ((size_t)(s * 8 + bhh) * N_ + nA) * 32 + quad * 8;
            const ushortx8 u = *(const ushortx8*)&Op[base];
            sa[0] += bf2f(u[0]); sa[1] += bf2f(u[1]);
            sa[2] += bf2f(u[2]); sa[3] += bf2f(u[3]);
            sb[0] += bf2f(u[4]); sb[1] += bf2f(u[5]);
            sb[2] += bf2f(u[6]); sb[3] += bf2f(u[7]);
            lt += bf2f(lp[(size_t)(s * 8 + bhh) * N_ + nA]);
        }
        const float inv = 1.f / lt;
        union { uint4 u; bf16x8 v; } cvt;
        cvt.u.x = pk2bf(sa[0] * inv, sa[1] * inv);
        cvt.u.y = pk2bf(sa[2] * inv, sa[3] * inv);
        cvt.u.z = pk2bf(sb[0] * inv, sb[1] * inv);
        cvt.u.w = pk2bf(sb[2] * inv, sb[3] * inv);
        af = cvt.v;
    }

    // ---- Wo partials (K = chans of head wv), all 8 nb
    #pragma unroll
    for (int nb = 0; nb < 8; ++nb) {
        const bf16x8 wf = *(const bf16x8*)(wo + (size_t)(nb * 16 + l15) * 128
                                           + wv * 32 + quad * 8);
        const f32x4 a = __builtin_amdgcn_mfma_f32_16x16x32_bf16(
            af, wf, f32x4{0.f, 0.f, 0.f, 0.f}, 0, 0, 0);
        *(f32x4*)&sred[wv][lane][nb * 4] = a;
    }
    __syncthreads();

    // ---- reduce own col-slice (nb = 2wv, 2wv+1), + bias + residual -> out1
    float v[2][4];
    #pragma unroll
    for (int lnb = 0; lnb < 2; ++lnb) {
        const int nbg = 2 * wv + lnb;
        f32x4 p = *(const f32x4*)&sred[0][lane][nbg * 4];
        p += *(const f32x4*)&sred[1][lane][nbg * 4];
        p += *(const f32x4*)&sred[2][lane][nbg * 4];
        p += *(const f32x4*)&sred[3][lane][nbg * 4];
        const int col = nbg * 16 + l15;
        const float bz = bo[col];
        #pragma unroll
        for (int r = 0; r < 4; ++r) {
            const int tok = m0 + quad * 4 + r;
            v[lnb][r] = p[r] + bz + bf2f(decb[(size_t)tok * 128 + col]);
        }
    }

    // ---- LN partial sums over this wave's 32 cols
    {
        float s[4], ss[4];
        #pragma unroll
        for (int r = 0; r < 4; ++r) {
            float a = v[0][r] + v[1][r];
            float b = v[0][r] * v[0][r] + v[1][r] * v[1][r];
            for (int m = 1; m < 16; m <<= 1) {
                a += __shfl_xor(a, m);
                b += __shfl_xor(b, m);
            }
            s[r] = a; ss[r] = b;
        }
        if (l15 == 0) {
            #pragma unroll
            for (int r = 0; r < 4; ++r) {
                sln[wv][0][quad * 4 + r] = s[r];
                sln[wv][1][quad * 4 + r] = ss[r];
            }
        }
    }
    __syncthreads();

    // ---- full LN stats, normalize own slice -> hb_lds
    {
        #pragma unroll
        for (int r = 0; r < 4; ++r) {
            const int tk = quad * 4 + r;
            const float stot  = sln[0][0][tk] + sln[1][0][tk] + sln[2][0][tk] + sln[3][0][tk];
            const float sstot = sln[0][1][tk] + sln[1][1][tk] + sln[2][1][tk] + sln[3][1][tk];
            const float mu  = stot * (1.f / 128.f);
            const float inv = rsqrtf(sstot * (1.f / 128.f) - mu * mu + 1e-5f);
            #pragma unroll
            for (int lnb = 0; lnb < 2; ++lnb) {
                const int col = (2 * wv + lnb) * 16 + l15;
                hb_lds[tk][col] = f2bf((v[lnb][r] - mu) * inv * g[col] + be[col]);
            }
        }
    }
    __syncthreads();

    // ---- FFN1: wave covers cols [wv*128, wv*128+128)
    bf16x8 hf[4];
    #pragma unroll
    for (int kk = 0; kk < 4; ++kk)
        hf[kk] = *(const bf16x8*)&hb_lds[l15][kk * 32 + quad * 8];
    #pragma unroll
    for (int nb = 0; nb < 8; ++nb) {
        const int col = wv * 128 + nb * 16 + l15;
        f32x4 a = {0.f, 0.f, 0.f, 0.f};
        #pragma unroll
        for (int kk = 0; kk < 4; ++kk) {
            const bf16x8 wf = *(const bf16x8*)(w1 + (size_t)col * 128 + kk * 32 + quad * 8);
            a = __builtin_amdgcn_mfma_f32_16x16x32_bf16(hf[kk], wf, a, 0, 0, 0);
        }
        const float bz = b1[col];
        #pragma unroll
        for (int r = 0; r < 4; ++r) {
            float x = a[r] + bz;
            x = 0.5f * x * (1.f + erff(x * 0.70710678118f));
            smid[quad * 4 + r][col] = f2bf(x);
        }
    }
    __syncthreads();

    // ---- FFN2: wave accumulates K-quarter [wv*128, wv*128+128), all 8 nb
    f32x4 acc[8];
    #pragma unroll
    for (int nb = 0; nb < 8; ++nb) acc[nb] = f32x4{0.f, 0.f, 0.f, 0.f};
    #pragma unroll
    for (int kk = 0; kk < 4; ++kk) {
        const bf16x8 af2 = *(const bf16x8*)&smid[l15][wv * 128 + kk * 32 + quad * 8];
        #pragma unroll
        for (int nb = 0; nb < 8; ++nb) {
            const bf16x8 wf = *(const bf16x8*)(w2 + (size_t)(nb * 16 + l15) * 512
                                               + wv * 128 + kk * 32 + quad * 8);
            acc[nb] = __builtin_amdgcn_mfma_f32_16x16x32_bf16(af2, wf, acc[nb], 0, 0, 0);
        }
    }
    #pragma unroll
    for (int nb = 0; nb < 8; ++nb)
        *(f32x4*)&sred[wv][lane][nb * 4] = acc[nb];
    __syncthreads();

    // ---- reduce own col-slice, + b2 + out1 residual, store [B,128,N] fp32
    {
        const int b = m0 >> 12;
        const int nb0 = (m0 & 4095) + quad * 4;
        #pragma unroll
        for (int lnb = 0; lnb < 2; ++lnb) {
            const int nbg = 2 * wv + lnb;
            f32x4 p = *(const f32x4*)&sred[0][lane][nbg * 4];
            p += *(const f32x4*)&sred[1][lane][nbg * 4];
            p += *(const f32x4*)&sred[2][lane][nbg * 4];
            p += *(const f32x4*)&sred[3][lane][nbg * 4];
            const int col = nbg * 16 + l15;
            const float bz = b2[col];
            f32x4 res;
            #pragma unroll
            for (int r = 0; r < 4; ++r)
                res[r] = p[r] + bz + v[lnb][r];
            *(f32x4*)&out[((size_t)(b * 128 + col)) * N_ + nb0] = res;
        }
    }
}

// ---------------------------------------------------------------------------
extern "C" void kernel_launch(void* const* d_in, const int* in_sizes, int n_in,
                              void* d_out, int out_size, void* d_ws, size_t ws_size,
                              hipStream_t stream) {
    const float* enc   = (const float*)d_in[0];
    const float* dec   = (const float*)d_in[1];
    const float* Wq    = (const float*)d_in[2];
    const float* bq    = (const float*)d_in[3];
    const float* Wk    = (const float*)d_in[4];
    const float* bk    = (const float*)d_in[5];
    const float* Wv    = (const float*)d_in[6];
    const float* bv    = (const float*)d_in[7];
    const float* Wo    = (const float*)d_in[8];
    const float* bo    = (const float*)d_in[9];
    const float* g_enc = (const float*)d_in[10];
    const float* b_enc = (const float*)d_in[11];
    const float* g_dec = (const float*)d_in[12];
    const float* b_dec = (const float*)d_in[13];
    const float* g_out = (const float*)d_in[14];
    const float* b_out = (const float*)d_in[15];
    const float* W1    = (const float*)d_in[16];
    const float* b1    = (const float*)d_in[17];
    const float* W2    = (const float*)d_in[18];
    const float* b2    = (const float*)d_in[19];
    float* out = (float*)d_out;
    char*  W   = (char*)d_ws;

    // workspace layout (27 MB, identical footprint to R6/R7 which passed)
    unsigned short* wqb = (unsigned short*)(W);
    unsigned short* wkb = wqb + 16384;
    unsigned short* wvb = wkb + 16384;
    unsigned short* wob = wvb + 16384;
    unsigned short* w1b = wob + 16384;
    unsigned short* w2b = w1b + 65536;                                  // ends 384 KB
    unsigned short* enc_lnb = (unsigned short*)(W + (512ull  << 10));   // [0.5, 2.5) MB
    unsigned short* dec_lnb = (unsigned short*)(W + (2560ull << 10));   // [2.5, 4.5)
    unsigned short* Qh      = (unsigned short*)(W + (4608ull << 10));   // [4.5, 6.5)
    unsigned short* Kh      = (unsigned short*)(W + (6656ull << 10));   // [6.5, 8.5)
    unsigned short* Vt      = (unsigned short*)(W + (8704ull << 10));   // [8.5, 10.5)
    unsigned short* Op      = (unsigned short*)(W + (10752ull << 10));  // 16 MB (SPLIT=8)
    unsigned short* lpb     = (unsigned short*)(W + (27136ull << 10));  // [26.5, 27)

    fused_pre_kernel<<<1280, 256, 0, stream>>>(
        Wq, Wk, Wv, Wo, W1, W2, wqb, wkb, wvb, wob, w1b, w2b,
        enc, dec, g_enc, b_enc, g_dec, b_dec, enc_lnb, dec_lnb);

    qkv_gemm_kernel<<<dim3(BN_ / 32, 3), 128, 0, stream>>>(
        dec_lnb, enc_lnb, wqb, wkb, wvb, bq, bk, bv, Qh, Kh, Vt);

    // 1024 blocks, XCD-affine: gid = qblk*64 + (s*8+bh) -> gid%8 == bh
    attn_kernel5<<<1024, 256, 0, stream>>>(Qh, Kh, Vt, Op, lpb);

    fused_tail2_kernel<<<512, 256, 0, stream>>>(Op, lpb, wob, bo, dec_lnb,
                                                g_out, b_out, w1b, b1, w2b, b2, out);
}

// Round 9
// 172.484 us; speedup vs baseline: 1.1175x; 1.0127x over previous
//
#include <hip/hip_runtime.h>
#include <hip/hip_bf16.h>
#include <math.h>

#define B_ 2
#define N_ 4096          // H*W*D
#define BN_ 8192
#define NH_ 4
#define SPLIT_ 8         // attention K-split

using bf16x8   = __attribute__((ext_vector_type(8))) __bf16;
using f32x4    = __attribute__((ext_vector_type(4))) float;
using ushortx8 = __attribute__((ext_vector_type(8))) unsigned short;

#if __has_builtin(__builtin_amdgcn_exp2f)
#define FAST_EXP2(x) __builtin_amdgcn_exp2f(x)
#else
#define FAST_EXP2(x) __expf((x) * 0.6931471805599453f)
#endif

static __device__ __forceinline__ unsigned short f2bf(float f) {
    union { __hip_bfloat16 h; unsigned short u; } c;
    c.h = __float2bfloat16(f);
    return c.u;
}
static __device__ __forceinline__ float bf2f(unsigned short u) {
    union { __hip_bfloat16 h; unsigned short u; } c;
    c.u = u;
    return __bfloat162float(c.h);
}
// pack two f32 -> two bf16 (round-biased truncate) in one v_perm_b32
static __device__ __forceinline__ unsigned int pk2bf(float lo, float hi) {
    return __builtin_amdgcn_perm(__float_as_uint(hi) + 0x8000u,
                                 __float_as_uint(lo) + 0x8000u, 0x07060302u);
}

// ---------------------------------------------------------------------------
// Convert all six weight matrices fp32 -> bf16.
// ---------------------------------------------------------------------------
__global__ __launch_bounds__(256)
void convert_weights_kernel(const float* __restrict__ Wq, const float* __restrict__ Wk,
                            const float* __restrict__ Wv, const float* __restrict__ Wo,
                            const float* __restrict__ W1, const float* __restrict__ W2,
                            unsigned short* __restrict__ wq, unsigned short* __restrict__ wk,
                            unsigned short* __restrict__ wv, unsigned short* __restrict__ wo,
                            unsigned short* __restrict__ w1, unsigned short* __restrict__ w2) {
    const int id = blockIdx.x * 256 + threadIdx.x;
    if      (id <  16384) wq[id]          = f2bf(Wq[id]);
    else if (id <  32768) wk[id - 16384]  = f2bf(Wk[id - 16384]);
    else if (id <  49152) wv[id - 32768]  = f2bf(Wv[id - 32768]);
    else if (id <  65536) wo[id - 49152]  = f2bf(Wo[id - 49152]);
    else if (id < 131072) w1[id - 65536]  = f2bf(W1[id - 65536]);
    else                  w2[id - 131072] = f2bf(W2[id - 131072]);
}

// ---------------------------------------------------------------------------
// Fused LN + QKV projection (no LN pre-pass, no enc_ln/dec_ln round trip).
// Reads raw fp32 [B,C,N]; each lane holds 32 chans of its token (l15), the
// 4 quads together hold all 128 -> LN stats via shfl_xor(16|32). A-frags
// packed in-register; Q pre-scaled by (1/sqrt d)*log2e; V written
// pre-transposed [bh, 32, n]. dec_ln side-written (z==0, half==0) for the
// tail's residual. Grid (BN/32, 3, 2): y = Q/K/V, z = output-chan half
// (4 nb per wave -> 2x TLP vs R8). 128 thr = 2 waves x 16 tokens.
// ---------------------------------------------------------------------------
__global__ __launch_bounds__(128)
void qkv_ln_kernel(const float* __restrict__ enc, const float* __restrict__ dec,
                   const float* __restrict__ g_enc, const float* __restrict__ b_enc,
                   const float* __restrict__ g_dec, const float* __restrict__ b_dec,
                   const unsigned short* __restrict__ wq,
                   const unsigned short* __restrict__ wk,
                   const unsigned short* __restrict__ wv,
                   const float* __restrict__ bq, const float* __restrict__ bk,
                   const float* __restrict__ bv,
                   unsigned short* __restrict__ Qh, unsigned short* __restrict__ Kh,
                   unsigned short* __restrict__ Vt,
                   unsigned short* __restrict__ dec_lnb) {
    const int z    = blockIdx.y;   // 0 Q(dec), 1 K(enc), 2 V(enc)
    const int half = blockIdx.z;   // output-chan half
    const int t = threadIdx.x;
    const int wvx = t >> 6, lane = t & 63;
    const int l15 = lane & 15, quad = lane >> 4;
    const int m0 = blockIdx.x * 32 + wvx * 16;
    const int b = m0 >> 12, n0 = m0 & 4095;
    const float* inb   = ((z == 0) ? dec : enc) + (size_t)b * 128 * N_;
    const float* gamma = (z == 0) ? g_dec : g_enc;
    const float* beta  = (z == 0) ? b_dec : b_enc;
    const unsigned short* Wb = (z == 0) ? wq : (z == 1) ? wk : wv;
    const float* bias        = (z == 0) ? bq : (z == 1) ? bk : bv;

    // load 32 chans of this lane's token, accumulate LN stats
    float x[4][8];
    float s = 0.f, ss = 0.f;
    #pragma unroll
    for (int kk = 0; kk < 4; ++kk) {
        #pragma unroll
        for (int j = 0; j < 8; ++j) {
            const int c = kk * 32 + quad * 8 + j;
            const float v = inb[(size_t)c * N_ + n0 + l15];
            x[kk][j] = v; s += v; ss += v * v;
        }
    }
    s  += __shfl_xor(s, 16);  s  += __shfl_xor(s, 32);
    ss += __shfl_xor(ss, 16); ss += __shfl_xor(ss, 32);
    const float mu  = s * (1.f / 128.f);
    const float inv = rsqrtf(ss * (1.f / 128.f) - mu * mu + 1e-5f);

    // normalize + affine + pack A-frags (and side-write dec_ln once)
    bf16x8 af[4];
    #pragma unroll
    for (int kk = 0; kk < 4; ++kk) {
        float y[8];
        #pragma unroll
        for (int j = 0; j < 8; ++j) {
            const int c = kk * 32 + quad * 8 + j;
            y[j] = (x[kk][j] - mu) * inv * gamma[c] + beta[c];
        }
        union { uint4 u; bf16x8 v8; ushortx8 us; } cvt;
        cvt.u.x = pk2bf(y[0], y[1]); cvt.u.y = pk2bf(y[2], y[3]);
        cvt.u.z = pk2bf(y[4], y[5]); cvt.u.w = pk2bf(y[6], y[7]);
        af[kk] = cvt.v8;
        if (z == 0 && half == 0)
            *(ushortx8*)(dec_lnb + (size_t)(m0 + l15) * 128 + kk * 32 + quad * 8) = cvt.us;
    }

    const float qsc = 0.17677669529663687f * 1.4426950408889634f;  // 1/sqrt(32)*log2e
    const int nb0 = n0 + quad * 4;
    #pragma unroll
    for (int nb = 0; nb < 4; ++nb) {
        const int col = half * 64 + nb * 16 + l15;
        f32x4 a = {0.f, 0.f, 0.f, 0.f};
        #pragma unroll
        for (int kk = 0; kk < 4; ++kk) {
            const bf16x8 wf = *(const bf16x8*)(Wb + (size_t)col * 128 + kk * 32 + quad * 8);
            a = __builtin_amdgcn_mfma_f32_16x16x32_bf16(af[kk], wf, a, 0, 0, 0);
        }
        const int h = col >> 5, d = col & 31;
        const float bz = bias[col];
        if (z == 2) {
            ushort4 pk;
            pk.x = f2bf(a[0] + bz);
            pk.y = f2bf(a[1] + bz);
            pk.z = f2bf(a[2] + bz);
            pk.w = f2bf(a[3] + bz);
            *(ushort4*)(Vt + ((size_t)(b * NH_ + h) * 32 + d) * N_ + nb0) = pk;
        } else {
            unsigned short* dst = (z == 0) ? Qh : Kh;
            const float sc = (z == 0) ? qsc : 1.f;
            #pragma unroll
            for (int r = 0; r < 4; ++r)
                dst[((size_t)(b * NH_ + h) * N_ + nb0 + r) * 32 + d] = f2bf((a[r] + bz) * sc);
        }
    }
}

// ---------------------------------------------------------------------------
// Split-K MFMA flash attention (R6-proven config): 64 q per wave (4 Q-frags),
// 256 q/block, 1024 blocks. XCD-affine 1-D grid: gid%8 == bh -> per-XCD K/V
// L2 residency. Max-free base-2 softmax; K prefetched one chunk ahead;
// sP wave-private (no barriers).
// ---------------------------------------------------------------------------
__global__ __launch_bounds__(256)
void attn_kernel5(const unsigned short* __restrict__ Qh,
                  const unsigned short* __restrict__ Kh,
                  const unsigned short* __restrict__ Vt,
                  unsigned short* __restrict__ Op,
                  unsigned short* __restrict__ lp) {
    __shared__ alignas(16) unsigned short sP[4][64][72];  // 36.9 KB

    const int gid   = blockIdx.x;
    const int combo = gid & 63;         // s*8 + bh
    const int qblk  = gid >> 6;         // 0..15
    const int bh    = combo & 7;
    const int s     = combo >> 3;
    const int t  = threadIdx.x;
    const int wvx = t >> 6, lane = t & 63;
    const int l15 = lane & 15, quad = lane >> 4;
    const int qw = qblk * 256 + wvx * 64;
    const size_t hbse = (size_t)bh * N_ * 32;

    bf16x8 qf[4];
    #pragma unroll
    for (int f = 0; f < 4; ++f)
        qf[f] = *(const bf16x8*)(Qh + hbse + (size_t)(qw + f * 16 + l15) * 32 + quad * 8);

    const unsigned short* Kp = Kh + hbse;
    const unsigned short* Vp = Vt + (size_t)bh * 32 * N_;

    f32x4 o0[4], o1[4];
    float l[4];
    #pragma unroll
    for (int f = 0; f < 4; ++f) {
        o0[f] = f32x4{0.f, 0.f, 0.f, 0.f};
        o1[f] = f32x4{0.f, 0.f, 0.f, 0.f};
        l[f] = 0.f;
    }
    const f32x4 zero = {0.f, 0.f, 0.f, 0.f};

    const int kbeg = s * (N_ / SPLIT_);
    const int kend = kbeg + (N_ / SPLIT_);

    bf16x8 kf[4];
    #pragma unroll
    for (int c = 0; c < 4; ++c)
        kf[c] = *(const bf16x8*)(Kp + (size_t)(kbeg + c * 16 + l15) * 32 + quad * 8);

    for (int k0 = kbeg; k0 < kend; k0 += 64) {
        bf16x8 va[2], vb[2];
        #pragma unroll
        for (int s2 = 0; s2 < 2; ++s2) {
            va[s2] = *(const bf16x8*)(Vp + (size_t)l15 * N_        + k0 + s2 * 32 + quad * 8);
            vb[s2] = *(const bf16x8*)(Vp + (size_t)(16 + l15) * N_ + k0 + s2 * 32 + quad * 8);
        }
        const int kn = (k0 + 64 < kend) ? (k0 + 64) : kbeg;
        bf16x8 kfn[4];
        #pragma unroll
        for (int c = 0; c < 4; ++c)
            kfn[c] = *(const bf16x8*)(Kp + (size_t)(kn + c * 16 + l15) * 32 + quad * 8);

        #pragma unroll
        for (int f = 0; f < 4; ++f) {
            #pragma unroll
            for (int c = 0; c < 4; ++c) {
                const f32x4 sv = __builtin_amdgcn_mfma_f32_16x16x32_bf16(kf[c], qf[f], zero, 0, 0, 0);
                const float p0 = FAST_EXP2(sv[0]);
                const float p1 = FAST_EXP2(sv[1]);
                const float p2 = FAST_EXP2(sv[2]);
                const float p3 = FAST_EXP2(sv[3]);
                l[f] += (p0 + p1) + (p2 + p3);
                uint2 pk;
                pk.x = pk2bf(p0, p1);
                pk.y = pk2bf(p2, p3);
                *(uint2*)&sP[wvx][f * 16 + l15][c * 16 + quad * 4] = pk;
            }
        }
        #pragma unroll
        for (int f = 0; f < 4; ++f) {
            #pragma unroll
            for (int s2 = 0; s2 < 2; ++s2) {
                const bf16x8 pf = *(const bf16x8*)&sP[wvx][f * 16 + l15][s2 * 32 + quad * 8];
                o0[f] = __builtin_amdgcn_mfma_f32_16x16x32_bf16(va[s2], pf, o0[f], 0, 0, 0);
                o1[f] = __builtin_amdgcn_mfma_f32_16x16x32_bf16(vb[s2], pf, o1[f], 0, 0, 0);
            }
        }
        #pragma unroll
        for (int c = 0; c < 4; ++c) kf[c] = kfn[c];
    }

    #pragma unroll
    for (int f = 0; f < 4; ++f) {
        float lf = l[f];
        lf += __shfl_xor(lf, 16);
        lf += __shfl_xor(lf, 32);
        const int tok = qw + f * 16 + l15;
        const size_t ob = ((size_t)(s * 8 + bh) * N_ + tok) * 32;
        uint2 w0, w1v;
        w0.x  = pk2bf(o0[f][0], o0[f][1]); w0.y  = pk2bf(o0[f][2], o0[f][3]);
        w1v.x = pk2bf(o1[f][0], o1[f][1]); w1v.y = pk2bf(o1[f][2], o1[f][3]);
        *(uint2*)&Op[ob + quad * 4]      = w0;
        *(uint2*)&Op[ob + 16 + quad * 4] = w1v;
        if (quad == 0)
            lp[(size_t)(s * 8 + bh) * N_ + tok] = f2bf(lf);
    }
}

// ---------------------------------------------------------------------------
// Fused tail v2: combine + Wo + residual + LN + FFN1(gelu) + FFN2 + residual
// -> [B,128,N] fp32. 512 blocks x 16 tokens; 4 waves = 4-way K-split in every
// GEMM phase. out1 in registers; hb/mid via LDS only.
// ---------------------------------------------------------------------------
__global__ __launch_bounds__(256)
void fused_tail2_kernel(const unsigned short* __restrict__ Op,
                        const unsigned short* __restrict__ lp,
                        const unsigned short* __restrict__ wo,
                        const float* __restrict__ bo,
                        const unsigned short* __restrict__ decb,
                        const float* __restrict__ g, const float* __restrict__ be,
                        const unsigned short* __restrict__ w1,
                        const float* __restrict__ b1,
                        const unsigned short* __restrict__ w2,
                        const float* __restrict__ b2,
                        float* __restrict__ out) {
    __shared__ alignas(16) float sred[4][64][32];              // 32 KB
    __shared__ float sln[4][2][16];                            // 0.5 KB
    __shared__ alignas(16) unsigned short hb_lds[16][136];     // 4.25 KB
    __shared__ alignas(16) unsigned short smid[16][536];       // 16.75 KB
    const int t = threadIdx.x;
    const int wv = t >> 6, lane = t & 63;
    const int l15 = lane & 15, quad = lane >> 4;
    const int m0 = blockIdx.x * 16;

    // ---- combine (head wv) + Wo A-frag
    const int tokA = m0 + l15;
    const int bA = tokA >> 12, nA = tokA & 4095;
    const int bhh = bA * NH_ + wv;
    bf16x8 af;
    {
        f32x4 sa = {0.f, 0.f, 0.f, 0.f}, sb = {0.f, 0.f, 0.f, 0.f};
        float lt = 0.f;
        #pragma unroll
        for (int s = 0; s < SPLIT_; ++s) {
            const size_t base = ((size_t)(s * 8 + bhh) * N_ + nA) * 32 + quad * 8;
            const ushortx8 u = *(const ushortx8*)&Op[base];
            sa[0] += bf2f(u[0]); sa[1] += bf2f(u[1]);
            sa[2] += bf2f(u[2]); sa[3] += bf2f(u[3]);
            sb[0] += bf2f(u[4]); sb[1] += bf2f(u[5]);
            sb[2] += bf2f(u[6]); sb[3] += bf2f(u[7]);
            lt += bf2f(lp[(size_t)(s * 8 + bhh) * N_ + nA]);
        }
        const float inv = 1.f / lt;
        union { uint4 u; bf16x8 v; } cvt;
        cvt.u.x = pk2bf(sa[0] * inv, sa[1] * inv);
        cvt.u.y = pk2bf(sa[2] * inv, sa[3] * inv);
        cvt.u.z = pk2bf(sb[0] * inv, sb[1] * inv);
        cvt.u.w = pk2bf(sb[2] * inv, sb[3] * inv);
        af = cvt.v;
    }

    // ---- Wo partials (K = chans of head wv), all 8 nb
    #pragma unroll
    for (int nb = 0; nb < 8; ++nb) {
        const bf16x8 wf = *(const bf16x8*)(wo + (size_t)(nb * 16 + l15) * 128
                                           + wv * 32 + quad * 8);
        const f32x4 a = __builtin_amdgcn_mfma_f32_16x16x32_bf16(
            af, wf, f32x4{0.f, 0.f, 0.f, 0.f}, 0, 0, 0);
        *(f32x4*)&sred[wv][lane][nb * 4] = a;
    }
    __syncthreads();

    // ---- reduce own col-slice (nb = 2wv, 2wv+1), + bias + residual -> out1
    float v[2][4];
    #pragma unroll
    for (int lnb = 0; lnb < 2; ++lnb) {
        const int nbg = 2 * wv + lnb;
        f32x4 p = *(const f32x4*)&sred[0][lane][nbg * 4];
        p += *(const f32x4*)&sred[1][lane][nbg * 4];
        p += *(const f32x4*)&sred[2][lane][nbg * 4];
        p += *(const f32x4*)&sred[3][lane][nbg * 4];
        const int col = nbg * 16 + l15;
        const float bz = bo[col];
        #pragma unroll
        for (int r = 0; r < 4; ++r) {
            const int tok = m0 + quad * 4 + r;
            v[lnb][r] = p[r] + bz + bf2f(decb[(size_t)tok * 128 + col]);
        }
    }

    // ---- LN partial sums over this wave's 32 cols
    {
        float s[4], ss[4];
        #pragma unroll
        for (int r = 0; r < 4; ++r) {
            float a = v[0][r] + v[1][r];
            float b = v[0][r] * v[0][r] + v[1][r] * v[1][r];
            for (int m = 1; m < 16; m <<= 1) {
                a += __shfl_xor(a, m);
                b += __shfl_xor(b, m);
            }
            s[r] = a; ss[r] = b;
        }
        if (l15 == 0) {
            #pragma unroll
            for (int r = 0; r < 4; ++r) {
                sln[wv][0][quad * 4 + r] = s[r];
                sln[wv][1][quad * 4 + r] = ss[r];
            }
        }
    }
    __syncthreads();

    // ---- full LN stats, normalize own slice -> hb_lds
    {
        #pragma unroll
        for (int r = 0; r < 4; ++r) {
            const int tk = quad * 4 + r;
            const float stot  = sln[0][0][tk] + sln[1][0][tk] + sln[2][0][tk] + sln[3][0][tk];
            const float sstot = sln[0][1][tk] + sln[1][1][tk] + sln[2][1][tk] + sln[3][1][tk];
            const float mu  = stot * (1.f / 128.f);
            const float inv = rsqrtf(sstot * (1.f / 128.f) - mu * mu + 1e-5f);
            #pragma unroll
            for (int lnb = 0; lnb < 2; ++lnb) {
                const int col = (2 * wv + lnb) * 16 + l15;
                hb_lds[tk][col] = f2bf((v[lnb][r] - mu) * inv * g[col] + be[col]);
            }
        }
    }
    __syncthreads();

    // ---- FFN1: wave covers cols [wv*128, wv*128+128)
    bf16x8 hf[4];
    #pragma unroll
    for (int kk = 0; kk < 4; ++kk)
        hf[kk] = *(const bf16x8*)&hb_lds[l15][kk * 32 + quad * 8];
    #pragma unroll
    for (int nb = 0; nb < 8; ++nb) {
        const int col = wv * 128 + nb * 16 + l15;
        f32x4 a = {0.f, 0.f, 0.f, 0.f};
        #pragma unroll
        for (int kk = 0; kk < 4; ++kk) {
            const bf16x8 wf = *(const bf16x8*)(w1 + (size_t)col * 128 + kk * 32 + quad * 8);
            a = __builtin_amdgcn_mfma_f32_16x16x32_bf16(hf[kk], wf, a, 0, 0, 0);
        }
        const float bz = b1[col];
        #pragma unroll
        for (int r = 0; r < 4; ++r) {
            float x = a[r] + bz;
            x = 0.5f * x * (1.f + erff(x * 0.70710678118f));
            smid[quad * 4 + r][col] = f2bf(x);
        }
    }
    __syncthreads();

    // ---- FFN2: wave accumulates K-quarter [wv*128, wv*128+128), all 8 nb
    f32x4 acc[8];
    #pragma unroll
    for (int nb = 0; nb < 8; ++nb) acc[nb] = f32x4{0.f, 0.f, 0.f, 0.f};
    #pragma unroll
    for (int kk = 0; kk < 4; ++kk) {
        const bf16x8 af2 = *(const bf16x8*)&smid[l15][wv * 128 + kk * 32 + quad * 8];
        #pragma unroll
        for (int nb = 0; nb < 8; ++nb) {
            const bf16x8 wf = *(const bf16x8*)(w2 + (size_t)(nb * 16 + l15) * 512
                                               + wv * 128 + kk * 32 + quad * 8);
            acc[nb] = __builtin_amdgcn_mfma_f32_16x16x32_bf16(af2, wf, acc[nb], 0, 0, 0);
        }
    }
    #pragma unroll
    for (int nb = 0; nb < 8; ++nb)
        *(f32x4*)&sred[wv][lane][nb * 4] = acc[nb];
    __syncthreads();

    // ---- reduce own col-slice, + b2 + out1 residual, store [B,128,N] fp32
    {
        const int b = m0 >> 12;
        const int nb0 = (m0 & 4095) + quad * 4;
        #pragma unroll
        for (int lnb = 0; lnb < 2; ++lnb) {
            const int nbg = 2 * wv + lnb;
            f32x4 p = *(const f32x4*)&sred[0][lane][nbg * 4];
            p += *(const f32x4*)&sred[1][lane][nbg * 4];
            p += *(const f32x4*)&sred[2][lane][nbg * 4];
            p += *(const f32x4*)&sred[3][lane][nbg * 4];
            const int col = nbg * 16 + l15;
            const float bz = b2[col];
            f32x4 res;
            #pragma unroll
            for (int r = 0; r < 4; ++r)
                res[r] = p[r] + bz + v[lnb][r];
            *(f32x4*)&out[((size_t)(b * 128 + col)) * N_ + nb0] = res;
        }
    }
}

// ---------------------------------------------------------------------------
extern "C" void kernel_launch(void* const* d_in, const int* in_sizes, int n_in,
                              void* d_out, int out_size, void* d_ws, size_t ws_size,
                              hipStream_t stream) {
    const float* enc   = (const float*)d_in[0];
    const float* dec   = (const float*)d_in[1];
    const float* Wq    = (const float*)d_in[2];
    const float* bq    = (const float*)d_in[3];
    const float* Wk    = (const float*)d_in[4];
    const float* bk    = (const float*)d_in[5];
    const float* Wv    = (const float*)d_in[6];
    const float* bv    = (const float*)d_in[7];
    const float* Wo    = (const float*)d_in[8];
    const float* bo    = (const float*)d_in[9];
    const float* g_enc = (const float*)d_in[10];
    const float* b_enc = (const float*)d_in[11];
    const float* g_dec = (const float*)d_in[12];
    const float* b_dec = (const float*)d_in[13];
    const float* g_out = (const float*)d_in[14];
    const float* b_out = (const float*)d_in[15];
    const float* W1    = (const float*)d_in[16];
    const float* b1    = (const float*)d_in[17];
    const float* W2    = (const float*)d_in[18];
    const float* b2    = (const float*)d_in[19];
    float* out = (float*)d_out;
    char*  W   = (char*)d_ws;

    // workspace layout (27 MB, identical footprint to prior passing rounds)
    unsigned short* wqb = (unsigned short*)(W);
    unsigned short* wkb = wqb + 16384;
    unsigned short* wvb = wkb + 16384;
    unsigned short* wob = wvb + 16384;
    unsigned short* w1b = wob + 16384;
    unsigned short* w2b = w1b + 65536;                                  // ends 384 KB
    unsigned short* dec_lnb = (unsigned short*)(W + (2560ull << 10));   // [2.5, 4.5) MB
    unsigned short* Qh      = (unsigned short*)(W + (4608ull << 10));   // [4.5, 6.5)
    unsigned short* Kh      = (unsigned short*)(W + (6656ull << 10));   // [6.5, 8.5)
    unsigned short* Vt      = (unsigned short*)(W + (8704ull << 10));   // [8.5, 10.5)
    unsigned short* Op      = (unsigned short*)(W + (10752ull << 10));  // 16 MB (SPLIT=8)
    unsigned short* lpb     = (unsigned short*)(W + (27136ull << 10));  // [26.5, 27)

    convert_weights_kernel<<<768, 256, 0, stream>>>(Wq, Wk, Wv, Wo, W1, W2,
                                                    wqb, wkb, wvb, wob, w1b, w2b);

    qkv_ln_kernel<<<dim3(BN_ / 32, 3, 2), 128, 0, stream>>>(
        enc, dec, g_enc, b_enc, g_dec, b_dec, wqb, wkb, wvb,
        bq, bk, bv, Qh, Kh, Vt, dec_lnb);

    // 1024 blocks, XCD-affine: gid = qblk*64 + (s*8+bh) -> gid%8 == bh
    attn_kernel5<<<1024, 256, 0, stream>>>(Qh, Kh, Vt, Op, lpb);

    fused_tail2_kernel<<<512, 256, 0, stream>>>(Op, lpb, wob, bo, dec_lnb,
                                                g_out, b_out, w1b, b1, w2b, b2, out);
}

// Round 10
// 167.615 us; speedup vs baseline: 1.1499x; 1.0291x over previous
//
#include <hip/hip_runtime.h>
#include <hip/hip_bf16.h>
#include <math.h>

#define B_ 2
#define N_ 4096          // H*W*D
#define BN_ 8192
#define NH_ 4
#define SPLIT_ 8         // attention K-split

using bf16x8   = __attribute__((ext_vector_type(8))) __bf16;
using f32x4    = __attribute__((ext_vector_type(4))) float;
using ushortx8 = __attribute__((ext_vector_type(8))) unsigned short;

#if __has_builtin(__builtin_amdgcn_exp2f)
#define FAST_EXP2(x) __builtin_amdgcn_exp2f(x)
#else
#define FAST_EXP2(x) __expf((x) * 0.6931471805599453f)
#endif

static __device__ __forceinline__ unsigned short f2bf(float f) {
    union { __hip_bfloat16 h; unsigned short u; } c;
    c.h = __float2bfloat16(f);
    return c.u;
}
static __device__ __forceinline__ float bf2f(unsigned short u) {
    union { __hip_bfloat16 h; unsigned short u; } c;
    c.u = u;
    return __bfloat162float(c.h);
}
// pack two f32 -> two bf16 (round-biased truncate) in one v_perm_b32
static __device__ __forceinline__ unsigned int pk2bf(float lo, float hi) {
    return __builtin_amdgcn_perm(__float_as_uint(hi) + 0x8000u,
                                 __float_as_uint(lo) + 0x8000u, 0x07060302u);
}

// ---------------------------------------------------------------------------
// Convert all six weight matrices fp32 -> bf16.
// ---------------------------------------------------------------------------
__global__ __launch_bounds__(256)
void convert_weights_kernel(const float* __restrict__ Wq, const float* __restrict__ Wk,
                            const float* __restrict__ Wv, const float* __restrict__ Wo,
                            const float* __restrict__ W1, const float* __restrict__ W2,
                            unsigned short* __restrict__ wq, unsigned short* __restrict__ wk,
                            unsigned short* __restrict__ wv, unsigned short* __restrict__ wo,
                            unsigned short* __restrict__ w1, unsigned short* __restrict__ w2) {
    const int id = blockIdx.x * 256 + threadIdx.x;
    if      (id <  16384) wq[id]          = f2bf(Wq[id]);
    else if (id <  32768) wk[id - 16384]  = f2bf(Wk[id - 16384]);
    else if (id <  49152) wv[id - 32768]  = f2bf(Wv[id - 32768]);
    else if (id <  65536) wo[id - 49152]  = f2bf(Wo[id - 49152]);
    else if (id < 131072) w1[id - 65536]  = f2bf(W1[id - 65536]);
    else                  w2[id - 131072] = f2bf(W2[id - 131072]);
}

// ---------------------------------------------------------------------------
// QKV v3: LDS-staged, dedup'd LN + projection.
// Grid (BN/32, 2), 256 thr. Block stages its 32-token x 128-chan fp32 tile
// (coalesced 128B rows), computes LN stats once, then 4 waves build LN'd
// A-frags from LDS:
//   z=0 (dec): wave w -> tokens (w&1)*16, Q cols (w>>1)*64; col-half 0 waves
//              also side-write dec_ln (bf16).
//   z=1 (enc): waves 0,1 -> K (full 128 cols); waves 2,3 -> V (transposed).
// Q pre-scaled by (1/sqrt d)*log2e for base-2 softmax.
// ---------------------------------------------------------------------------
__global__ __launch_bounds__(256)
void qkv2_kernel(const float* __restrict__ enc, const float* __restrict__ dec,
                 const float* __restrict__ g_enc, const float* __restrict__ b_enc,
                 const float* __restrict__ g_dec, const float* __restrict__ b_dec,
                 const unsigned short* __restrict__ wq,
                 const unsigned short* __restrict__ wk,
                 const unsigned short* __restrict__ wv,
                 const float* __restrict__ bq, const float* __restrict__ bk,
                 const float* __restrict__ bv,
                 unsigned short* __restrict__ Qh, unsigned short* __restrict__ Kh,
                 unsigned short* __restrict__ Vt,
                 unsigned short* __restrict__ dec_lnb) {
    __shared__ float tile[128][33];
    __shared__ float mu_s[32], inv_s[32];
    const int z  = blockIdx.y;
    const int t  = threadIdx.x;
    const int m0 = blockIdx.x * 32;
    const int b  = m0 >> 12, n0 = m0 & 4095;
    const float* inb   = ((z == 0) ? dec : enc) + (size_t)b * 128 * N_;
    const float* gamma = (z == 0) ? g_dec : g_enc;
    const float* beta  = (z == 0) ? b_dec : b_enc;

    // stage: 128 chans x 32 tokens, 128B-coalesced along n
    {
        const int col = t & 31;
        const int r0  = t >> 5;
        #pragma unroll
        for (int j = 0; j < 16; ++j) {
            const int r = r0 + 8 * j;
            tile[r][col] = inb[(size_t)r * N_ + n0 + col];
        }
    }
    __syncthreads();
    // LN stats: 8 threads per token
    {
        const int tok = t >> 3;
        const int ln  = t & 7;
        float s = 0.f, ss = 0.f;
        for (int c = ln; c < 128; c += 8) {
            const float x = tile[c][tok];
            s += x; ss += x * x;
        }
        for (int m = 1; m < 8; m <<= 1) {
            s  += __shfl_xor(s, m);
            ss += __shfl_xor(ss, m);
        }
        if (ln == 0) {
            const float mu  = s * (1.f / 128.f);
            mu_s[tok]  = mu;
            inv_s[tok] = rsqrtf(ss * (1.f / 128.f) - mu * mu + 1e-5f);
        }
    }
    __syncthreads();

    const int wvx = t >> 6, lane = t & 63;
    const int l15 = lane & 15, quad = lane >> 4;
    const int tokgrp  = (wvx & 1) * 16;
    const int colbase = (z == 0) ? (wvx >> 1) * 64 : 0;
    const bool isV    = (z == 1) && (wvx >> 1);
    const bool wrLN   = (z == 0) && ((wvx >> 1) == 0);
    const int nbCount = (z == 0) ? 4 : 8;
    const int tok = tokgrp + l15;
    const float mu  = mu_s[tok];
    const float inv = inv_s[tok];

    // build LN'd A-frags straight from LDS
    bf16x8 af[4];
    #pragma unroll
    for (int kk = 0; kk < 4; ++kk) {
        float y[8];
        #pragma unroll
        for (int j = 0; j < 8; ++j) {
            const int c = kk * 32 + quad * 8 + j;
            y[j] = (tile[c][tok] - mu) * inv * gamma[c] + beta[c];
        }
        union { uint4 u; bf16x8 v8; ushortx8 us; } cvt;
        cvt.u.x = pk2bf(y[0], y[1]); cvt.u.y = pk2bf(y[2], y[3]);
        cvt.u.z = pk2bf(y[4], y[5]); cvt.u.w = pk2bf(y[6], y[7]);
        af[kk] = cvt.v8;
        if (wrLN)
            *(ushortx8*)(dec_lnb + (size_t)(m0 + tok) * 128 + kk * 32 + quad * 8) = cvt.us;
    }

    const unsigned short* Wb = (z == 0) ? wq : (isV ? wv : wk);
    const float* bias        = (z == 0) ? bq : (isV ? bv : bk);
    const float sc = (z == 0) ? (0.17677669529663687f * 1.4426950408889634f) : 1.f;
    const int nbase = n0 + tokgrp + quad * 4;

    #pragma unroll
    for (int nb = 0; nb < 8; ++nb) {
        if (nb >= nbCount) break;
        const int col = colbase + nb * 16 + l15;
        f32x4 a = {0.f, 0.f, 0.f, 0.f};
        #pragma unroll
        for (int kk = 0; kk < 4; ++kk) {
            const bf16x8 wf = *(const bf16x8*)(Wb + (size_t)col * 128 + kk * 32 + quad * 8);
            a = __builtin_amdgcn_mfma_f32_16x16x32_bf16(af[kk], wf, a, 0, 0, 0);
        }
        const int h = col >> 5, d = col & 31;
        const float bz = bias[col];
        if (isV) {
            ushort4 pk;
            pk.x = f2bf(a[0] + bz);
            pk.y = f2bf(a[1] + bz);
            pk.z = f2bf(a[2] + bz);
            pk.w = f2bf(a[3] + bz);
            *(ushort4*)(Vt + ((size_t)(b * NH_ + h) * 32 + d) * N_ + nbase) = pk;
        } else {
            unsigned short* dst = (z == 0) ? Qh : Kh;
            #pragma unroll
            for (int r = 0; r < 4; ++r)
                dst[((size_t)(b * NH_ + h) * N_ + nbase + r) * 32 + d] = f2bf((a[r] + bz) * sc);
        }
    }
}

// ---------------------------------------------------------------------------
// Split-K MFMA flash attention (R6-proven config): 64 q per wave (4 Q-frags),
// 256 q/block, 1024 blocks. XCD-affine 1-D grid: gid%8 == bh -> per-XCD K/V
// L2 residency. Max-free base-2 softmax; K prefetched one chunk ahead;
// sP wave-private (no barriers).
// ---------------------------------------------------------------------------
__global__ __launch_bounds__(256)
void attn_kernel5(const unsigned short* __restrict__ Qh,
                  const unsigned short* __restrict__ Kh,
                  const unsigned short* __restrict__ Vt,
                  unsigned short* __restrict__ Op,
                  unsigned short* __restrict__ lp) {
    __shared__ alignas(16) unsigned short sP[4][64][72];  // 36.9 KB

    const int gid   = blockIdx.x;
    const int combo = gid & 63;         // s*8 + bh
    const int qblk  = gid >> 6;         // 0..15
    const int bh    = combo & 7;
    const int s     = combo >> 3;
    const int t  = threadIdx.x;
    const int wvx = t >> 6, lane = t & 63;
    const int l15 = lane & 15, quad = lane >> 4;
    const int qw = qblk * 256 + wvx * 64;
    const size_t hbse = (size_t)bh * N_ * 32;

    bf16x8 qf[4];
    #pragma unroll
    for (int f = 0; f < 4; ++f)
        qf[f] = *(const bf16x8*)(Qh + hbse + (size_t)(qw + f * 16 + l15) * 32 + quad * 8);

    const unsigned short* Kp = Kh + hbse;
    const unsigned short* Vp = Vt + (size_t)bh * 32 * N_;

    f32x4 o0[4], o1[4];
    float l[4];
    #pragma unroll
    for (int f = 0; f < 4; ++f) {
        o0[f] = f32x4{0.f, 0.f, 0.f, 0.f};
        o1[f] = f32x4{0.f, 0.f, 0.f, 0.f};
        l[f] = 0.f;
    }
    const f32x4 zero = {0.f, 0.f, 0.f, 0.f};

    const int kbeg = s * (N_ / SPLIT_);
    const int kend = kbeg + (N_ / SPLIT_);

    bf16x8 kf[4];
    #pragma unroll
    for (int c = 0; c < 4; ++c)
        kf[c] = *(const bf16x8*)(Kp + (size_t)(kbeg + c * 16 + l15) * 32 + quad * 8);

    for (int k0 = kbeg; k0 < kend; k0 += 64) {
        bf16x8 va[2], vb[2];
        #pragma unroll
        for (int s2 = 0; s2 < 2; ++s2) {
            va[s2] = *(const bf16x8*)(Vp + (size_t)l15 * N_        + k0 + s2 * 32 + quad * 8);
            vb[s2] = *(const bf16x8*)(Vp + (size_t)(16 + l15) * N_ + k0 + s2 * 32 + quad * 8);
        }
        const int kn = (k0 + 64 < kend) ? (k0 + 64) : kbeg;
        bf16x8 kfn[4];
        #pragma unroll
        for (int c = 0; c < 4; ++c)
            kfn[c] = *(const bf16x8*)(Kp + (size_t)(kn + c * 16 + l15) * 32 + quad * 8);

        #pragma unroll
        for (int f = 0; f < 4; ++f) {
            #pragma unroll
            for (int c = 0; c < 4; ++c) {
                const f32x4 sv = __builtin_amdgcn_mfma_f32_16x16x32_bf16(kf[c], qf[f], zero, 0, 0, 0);
                const float p0 = FAST_EXP2(sv[0]);
                const float p1 = FAST_EXP2(sv[1]);
                const float p2 = FAST_EXP2(sv[2]);
                const float p3 = FAST_EXP2(sv[3]);
                l[f] += (p0 + p1) + (p2 + p3);
                uint2 pk;
                pk.x = pk2bf(p0, p1);
                pk.y = pk2bf(p2, p3);
                *(uint2*)&sP[wvx][f * 16 + l15][c * 16 + quad * 4] = pk;
            }
        }
        #pragma unroll
        for (int f = 0; f < 4; ++f) {
            #pragma unroll
            for (int s2 = 0; s2 < 2; ++s2) {
                const bf16x8 pf = *(const bf16x8*)&sP[wvx][f * 16 + l15][s2 * 32 + quad * 8];
                o0[f] = __builtin_amdgcn_mfma_f32_16x16x32_bf16(va[s2], pf, o0[f], 0, 0, 0);
                o1[f] = __builtin_amdgcn_mfma_f32_16x16x32_bf16(vb[s2], pf, o1[f], 0, 0, 0);
            }
        }
        #pragma unroll
        for (int c = 0; c < 4; ++c) kf[c] = kfn[c];
    }

    #pragma unroll
    for (int f = 0; f < 4; ++f) {
        float lf = l[f];
        lf += __shfl_xor(lf, 16);
        lf += __shfl_xor(lf, 32);
        const int tok = qw + f * 16 + l15;
        const size_t ob = ((size_t)(s * 8 + bh) * N_ + tok) * 32;
        uint2 w0, w1v;
        w0.x  = pk2bf(o0[f][0], o0[f][1]); w0.y  = pk2bf(o0[f][2], o0[f][3]);
        w1v.x = pk2bf(o1[f][0], o1[f][1]); w1v.y = pk2bf(o1[f][2], o1[f][3]);
        *(uint2*)&Op[ob + quad * 4]      = w0;
        *(uint2*)&Op[ob + 16 + quad * 4] = w1v;
        if (quad == 0)
            lp[(size_t)(s * 8 + bh) * N_ + tok] = f2bf(lf);
    }
}

// ---------------------------------------------------------------------------
// Fused tail v3: combine + Wo + residual + LN + FFN1(gelu) + FFN2 + residual
// -> [B,128,N] fp32. 512 blocks x 16 tokens; 4 waves = 4-way K-split in every
// GEMM phase. Partial-sum buffer in bf16 (stride 36 shorts: 8B-aligned rows,
// <=4-way banks) -> LDS 39.9 KB -> 4 blocks/CU (was 2).
// ---------------------------------------------------------------------------
__global__ __launch_bounds__(256)
void fused_tail3_kernel(const unsigned short* __restrict__ Op,
                        const unsigned short* __restrict__ lp,
                        const unsigned short* __restrict__ wo,
                        const float* __restrict__ bo,
                        const unsigned short* __restrict__ decb,
                        const float* __restrict__ g, const float* __restrict__ be,
                        const unsigned short* __restrict__ w1,
                        const float* __restrict__ b1,
                        const unsigned short* __restrict__ w2,
                        const float* __restrict__ b2,
                        float* __restrict__ out) {
    __shared__ alignas(16) unsigned short sredb[4][64][36];    // 18.4 KB (bf16 partials)
    __shared__ float sln[4][2][16];                            // 0.5 KB
    __shared__ alignas(16) unsigned short hb_lds[16][136];     // 4.25 KB
    __shared__ alignas(16) unsigned short smid[16][536];       // 16.75 KB
    const int t = threadIdx.x;
    const int wv = t >> 6, lane = t & 63;
    const int l15 = lane & 15, quad = lane >> 4;
    const int m0 = blockIdx.x * 16;

    // ---- combine (head wv) + Wo A-frag
    const int tokA = m0 + l15;
    const int bA = tokA >> 12, nA = tokA & 4095;
    const int bhh = bA * NH_ + wv;
    bf16x8 af;
    {
        f32x4 sa = {0.f, 0.f, 0.f, 0.f}, sb = {0.f, 0.f, 0.f, 0.f};
        float lt = 0.f;
        #pragma unroll
        for (int s = 0; s < SPLIT_; ++s) {
            const size_t base = ((size_t)(s * 8 + bhh) * N_ + nA) * 32 + quad * 8;
            const ushortx8 u = *(const ushortx8*)&Op[base];
            sa[0] += bf2f(u[0]); sa[1] += bf2f(u[1]);
            sa[2] += bf2f(u[2]); sa[3] += bf2f(u[3]);
            sb[0] += bf2f(u[4]); sb[1] += bf2f(u[5]);
            sb[2] += bf2f(u[6]); sb[3] += bf2f(u[7]);
            lt += bf2f(lp[(size_t)(s * 8 + bhh) * N_ + nA]);
        }
        const float inv = 1.f / lt;
        union { uint4 u; bf16x8 v; } cvt;
        cvt.u.x = pk2bf(sa[0] * inv, sa[1] * inv);
        cvt.u.y = pk2bf(sa[2] * inv, sa[3] * inv);
        cvt.u.z = pk2bf(sb[0] * inv, sb[1] * inv);
        cvt.u.w = pk2bf(sb[2] * inv, sb[3] * inv);
        af = cvt.v;
    }

    // ---- Wo partials (K = chans of head wv), all 8 nb, bf16-packed to LDS
    #pragma unroll
    for (int nb = 0; nb < 8; ++nb) {
        const bf16x8 wf = *(const bf16x8*)(wo + (size_t)(nb * 16 + l15) * 128
                                           + wv * 32 + quad * 8);
        const f32x4 a = __builtin_amdgcn_mfma_f32_16x16x32_bf16(
            af, wf, f32x4{0.f, 0.f, 0.f, 0.f}, 0, 0, 0);
        uint2 p;
        p.x = pk2bf(a[0], a[1]);
        p.y = pk2bf(a[2], a[3]);
        *(uint2*)&sredb[wv][lane][nb * 4] = p;
    }
    __syncthreads();

    // ---- reduce own col-slice (nb = 2wv, 2wv+1), + bias + residual -> out1
    float v[2][4];
    #pragma unroll
    for (int lnb = 0; lnb < 2; ++lnb) {
        const int nbg = 2 * wv + lnb;
        f32x4 p = {0.f, 0.f, 0.f, 0.f};
        #pragma unroll
        for (int w = 0; w < 4; ++w) {
            const ushort4 u = *(const ushort4*)&sredb[w][lane][nbg * 4];
            p[0] += bf2f(u.x); p[1] += bf2f(u.y);
            p[2] += bf2f(u.z); p[3] += bf2f(u.w);
        }
        const int col = nbg * 16 + l15;
        const float bz = bo[col];
        #pragma unroll
        for (int r = 0; r < 4; ++r) {
            const int tok = m0 + quad * 4 + r;
            v[lnb][r] = p[r] + bz + bf2f(decb[(size_t)tok * 128 + col]);
        }
    }

    // ---- LN partial sums over this wave's 32 cols
    {
        float s[4], ss[4];
        #pragma unroll
        for (int r = 0; r < 4; ++r) {
            float a = v[0][r] + v[1][r];
            float b = v[0][r] * v[0][r] + v[1][r] * v[1][r];
            for (int m = 1; m < 16; m <<= 1) {
                a += __shfl_xor(a, m);
                b += __shfl_xor(b, m);
            }
            s[r] = a; ss[r] = b;
        }
        if (l15 == 0) {
            #pragma unroll
            for (int r = 0; r < 4; ++r) {
                sln[wv][0][quad * 4 + r] = s[r];
                sln[wv][1][quad * 4 + r] = ss[r];
            }
        }
    }
    __syncthreads();

    // ---- full LN stats, normalize own slice -> hb_lds
    {
        #pragma unroll
        for (int r = 0; r < 4; ++r) {
            const int tk = quad * 4 + r;
            const float stot  = sln[0][0][tk] + sln[1][0][tk] + sln[2][0][tk] + sln[3][0][tk];
            const float sstot = sln[0][1][tk] + sln[1][1][tk] + sln[2][1][tk] + sln[3][1][tk];
            const float mu  = stot * (1.f / 128.f);
            const float inv = rsqrtf(sstot * (1.f / 128.f) - mu * mu + 1e-5f);
            #pragma unroll
            for (int lnb = 0; lnb < 2; ++lnb) {
                const int col = (2 * wv + lnb) * 16 + l15;
                hb_lds[tk][col] = f2bf((v[lnb][r] - mu) * inv * g[col] + be[col]);
            }
        }
    }
    __syncthreads();

    // ---- FFN1: wave covers cols [wv*128, wv*128+128)
    bf16x8 hf[4];
    #pragma unroll
    for (int kk = 0; kk < 4; ++kk)
        hf[kk] = *(const bf16x8*)&hb_lds[l15][kk * 32 + quad * 8];
    #pragma unroll
    for (int nb = 0; nb < 8; ++nb) {
        const int col = wv * 128 + nb * 16 + l15;
        f32x4 a = {0.f, 0.f, 0.f, 0.f};
        #pragma unroll
        for (int kk = 0; kk < 4; ++kk) {
            const bf16x8 wf = *(const bf16x8*)(w1 + (size_t)col * 128 + kk * 32 + quad * 8);
            a = __builtin_amdgcn_mfma_f32_16x16x32_bf16(hf[kk], wf, a, 0, 0, 0);
        }
        const float bz = b1[col];
        #pragma unroll
        for (int r = 0; r < 4; ++r) {
            float x = a[r] + bz;
            x = 0.5f * x * (1.f + erff(x * 0.70710678118f));
            smid[quad * 4 + r][col] = f2bf(x);
        }
    }
    __syncthreads();

    // ---- FFN2: wave accumulates K-quarter [wv*128, wv*128+128), all 8 nb
    f32x4 acc[8];
    #pragma unroll
    for (int nb = 0; nb < 8; ++nb) acc[nb] = f32x4{0.f, 0.f, 0.f, 0.f};
    #pragma unroll
    for (int kk = 0; kk < 4; ++kk) {
        const bf16x8 af2 = *(const bf16x8*)&smid[l15][wv * 128 + kk * 32 + quad * 8];
        #pragma unroll
        for (int nb = 0; nb < 8; ++nb) {
            const bf16x8 wf = *(const bf16x8*)(w2 + (size_t)(nb * 16 + l15) * 512
                                               + wv * 128 + kk * 32 + quad * 8);
            acc[nb] = __builtin_amdgcn_mfma_f32_16x16x32_bf16(af2, wf, acc[nb], 0, 0, 0);
        }
    }
    __syncthreads();   // hb/smid consumers done; reuse sredb
    #pragma unroll
    for (int nb = 0; nb < 8; ++nb) {
        uint2 p;
        p.x = pk2bf(acc[nb][0], acc[nb][1]);
        p.y = pk2bf(acc[nb][2], acc[nb][3]);
        *(uint2*)&sredb[wv][lane][nb * 4] = p;
    }
    __syncthreads();

    // ---- reduce own col-slice, + b2 + out1 residual, store [B,128,N] fp32
    {
        const int b = m0 >> 12;
        const int nb0 = (m0 & 4095) + quad * 4;
        #pragma unroll
        for (int lnb = 0; lnb < 2; ++lnb) {
            const int nbg = 2 * wv + lnb;
            f32x4 p = {0.f, 0.f, 0.f, 0.f};
            #pragma unroll
            for (int w = 0; w < 4; ++w) {
                const ushort4 u = *(const ushort4*)&sredb[w][lane][nbg * 4];
                p[0] += bf2f(u.x); p[1] += bf2f(u.y);
                p[2] += bf2f(u.z); p[3] += bf2f(u.w);
            }
            const int col = nbg * 16 + l15;
            const float bz = b2[col];
            f32x4 res;
            #pragma unroll
            for (int r = 0; r < 4; ++r)
                res[r] = p[r] + bz + v[lnb][r];
            *(f32x4*)&out[((size_t)(b * 128 + col)) * N_ + nb0] = res;
        }
    }
}

// ---------------------------------------------------------------------------
extern "C" void kernel_launch(void* const* d_in, const int* in_sizes, int n_in,
                              void* d_out, int out_size, void* d_ws, size_t ws_size,
                              hipStream_t stream) {
    const float* enc   = (const float*)d_in[0];
    const float* dec   = (const float*)d_in[1];
    const float* Wq    = (const float*)d_in[2];
    const float* bq    = (const float*)d_in[3];
    const float* Wk    = (const float*)d_in[4];
    const float* bk    = (const float*)d_in[5];
    const float* Wv    = (const float*)d_in[6];
    const float* bv    = (const float*)d_in[7];
    const float* Wo    = (const float*)d_in[8];
    const float* bo    = (const float*)d_in[9];
    const float* g_enc = (const float*)d_in[10];
    const float* b_enc = (const float*)d_in[11];
    const float* g_dec = (const float*)d_in[12];
    const float* b_dec = (const float*)d_in[13];
    const float* g_out = (const float*)d_in[14];
    const float* b_out = (const float*)d_in[15];
    const float* W1    = (const float*)d_in[16];
    const float* b1    = (const float*)d_in[17];
    const float* W2    = (const float*)d_in[18];
    const float* b2    = (const float*)d_in[19];
    float* out = (float*)d_out;
    char*  W   = (char*)d_ws;

    // workspace layout (27 MB, identical footprint to prior passing rounds)
    unsigned short* wqb = (unsigned short*)(W);
    unsigned short* wkb = wqb + 16384;
    unsigned short* wvb = wkb + 16384;
    unsigned short* wob = wvb + 16384;
    unsigned short* w1b = wob + 16384;
    unsigned short* w2b = w1b + 65536;                                  // ends 384 KB
    unsigned short* dec_lnb = (unsigned short*)(W + (2560ull << 10));   // [2.5, 4.5) MB
    unsigned short* Qh      = (unsigned short*)(W + (4608ull << 10));   // [4.5, 6.5)
    unsigned short* Kh      = (unsigned short*)(W + (6656ull << 10));   // [6.5, 8.5)
    unsigned short* Vt      = (unsigned short*)(W + (8704ull << 10));   // [8.5, 10.5)
    unsigned short* Op      = (unsigned short*)(W + (10752ull << 10));  // 16 MB (SPLIT=8)
    unsigned short* lpb     = (unsigned short*)(W + (27136ull << 10));  // [26.5, 27)

    convert_weights_kernel<<<768, 256, 0, stream>>>(Wq, Wk, Wv, Wo, W1, W2,
                                                    wqb, wkb, wvb, wob, w1b, w2b);

    qkv2_kernel<<<dim3(BN_ / 32, 2), 256, 0, stream>>>(
        enc, dec, g_enc, b_enc, g_dec, b_dec, wqb, wkb, wvb,
        bq, bk, bv, Qh, Kh, Vt, dec_lnb);

    // 1024 blocks, XCD-affine: gid = qblk*64 + (s*8+bh) -> gid%8 == bh
    attn_kernel5<<<1024, 256, 0, stream>>>(Qh, Kh, Vt, Op, lpb);

    fused_tail3_kernel<<<512, 256, 0, stream>>>(Op, lpb, wob, bo, dec_lnb,
                                                g_out, b_out, w1b, b1, w2b, b2, out);
}

// Round 11
// 165.954 us; speedup vs baseline: 1.1614x; 1.0100x over previous
//
#include <hip/hip_runtime.h>
#include <hip/hip_bf16.h>
#include <math.h>

#define B_ 2
#define N_ 4096          // H*W*D
#define BN_ 8192
#define NH_ 4
#define SPLIT_ 8         // attention K-split (in-block: 8 waves = 8 splits)

using bf16x8   = __attribute__((ext_vector_type(8))) __bf16;
using f32x4    = __attribute__((ext_vector_type(4))) float;
using ushortx8 = __attribute__((ext_vector_type(8))) unsigned short;

#if __has_builtin(__builtin_amdgcn_exp2f)
#define FAST_EXP2(x) __builtin_amdgcn_exp2f(x)
#else
#define FAST_EXP2(x) __expf((x) * 0.6931471805599453f)
#endif

static __device__ __forceinline__ unsigned short f2bf(float f) {
    union { __hip_bfloat16 h; unsigned short u; } c;
    c.h = __float2bfloat16(f);
    return c.u;
}
static __device__ __forceinline__ float bf2f(unsigned short u) {
    union { __hip_bfloat16 h; unsigned short u; } c;
    c.u = u;
    return __bfloat162float(c.h);
}
// pack two f32 -> two bf16 (round-biased truncate) in one v_perm_b32
static __device__ __forceinline__ unsigned int pk2bf(float lo, float hi) {
    return __builtin_amdgcn_perm(__float_as_uint(hi) + 0x8000u,
                                 __float_as_uint(lo) + 0x8000u, 0x07060302u);
}
// load 8 fp32 weights, convert to a bf16 A/B fragment in-register
static __device__ __forceinline__ bf16x8 ldw(const float* __restrict__ W, size_t off) {
    const float4 a = *(const float4*)(W + off);
    const float4 b = *(const float4*)(W + off + 4);
    union { uint4 u; bf16x8 v; } c;
    c.u.x = pk2bf(a.x, a.y); c.u.y = pk2bf(a.z, a.w);
    c.u.z = pk2bf(b.x, b.y); c.u.w = pk2bf(b.z, b.w);
    return c.v;
}

// ---------------------------------------------------------------------------
// QKV v4: LDS-staged LN + projection with INLINE fp32->bf16 weight conversion
// (no separate convert pass for wq/wk/wv). Extra blocks (gid>=512) convert
// wo/w1/w2 for the tail kernel.
// Blocks 0..511: (m = gid&255 -> 32 tokens, z = gid>>8 -> dec(QV? no: z=0 dec/Q,
// z=1 enc/K+V). 256 thr.
// ---------------------------------------------------------------------------
__global__ __launch_bounds__(256)
void qkv3_kernel(const float* __restrict__ enc, const float* __restrict__ dec,
                 const float* __restrict__ g_enc, const float* __restrict__ b_enc,
                 const float* __restrict__ g_dec, const float* __restrict__ b_dec,
                 const float* __restrict__ Wq, const float* __restrict__ Wk,
                 const float* __restrict__ Wv,
                 const float* __restrict__ bq, const float* __restrict__ bk,
                 const float* __restrict__ bv,
                 const float* __restrict__ Wo, const float* __restrict__ W1,
                 const float* __restrict__ W2,
                 unsigned short* __restrict__ wo, unsigned short* __restrict__ w1,
                 unsigned short* __restrict__ w2,
                 unsigned short* __restrict__ Qh, unsigned short* __restrict__ Kh,
                 unsigned short* __restrict__ Vt,
                 unsigned short* __restrict__ dec_lnb) {
    const int t = threadIdx.x;
    if (blockIdx.x >= 512) {
        // ---- weight conversion for the tail: wo(16384) w1(65536) w2(65536)
        const int e = ((int)blockIdx.x - 512) * 256 * 8 + t * 8;
        const float* src; unsigned short* dst; int off;
        if (e < 16384)       { src = Wo; dst = wo; off = e; }
        else if (e < 81920)  { src = W1; dst = w1; off = e - 16384; }
        else                 { src = W2; dst = w2; off = e - 81920; }
        const float4 a = *(const float4*)(src + off);
        const float4 b = *(const float4*)(src + off + 4);
        uint4 p;
        p.x = pk2bf(a.x, a.y); p.y = pk2bf(a.z, a.w);
        p.z = pk2bf(b.x, b.y); p.w = pk2bf(b.z, b.w);
        *(uint4*)(dst + off) = p;
        return;
    }
    __shared__ float tile[128][33];
    __shared__ float mu_s[32], inv_s[32];
    const int z  = blockIdx.x >> 8;       // 0 dec/Q, 1 enc/K+V
    const int m0 = (blockIdx.x & 255) * 32;
    const int b  = m0 >> 12, n0 = m0 & 4095;
    const float* inb   = ((z == 0) ? dec : enc) + (size_t)b * 128 * N_;
    const float* gamma = (z == 0) ? g_dec : g_enc;
    const float* beta  = (z == 0) ? b_dec : b_enc;

    // stage: 128 chans x 32 tokens, 128B-coalesced along n
    {
        const int col = t & 31;
        const int r0  = t >> 5;
        #pragma unroll
        for (int j = 0; j < 16; ++j) {
            const int r = r0 + 8 * j;
            tile[r][col] = inb[(size_t)r * N_ + n0 + col];
        }
    }
    __syncthreads();
    // LN stats: 8 threads per token
    {
        const int tok = t >> 3;
        const int ln  = t & 7;
        float s = 0.f, ss = 0.f;
        for (int c = ln; c < 128; c += 8) {
            const float x = tile[c][tok];
            s += x; ss += x * x;
        }
        for (int m = 1; m < 8; m <<= 1) {
            s  += __shfl_xor(s, m);
            ss += __shfl_xor(ss, m);
        }
        if (ln == 0) {
            const float mu  = s * (1.f / 128.f);
            mu_s[tok]  = mu;
            inv_s[tok] = rsqrtf(ss * (1.f / 128.f) - mu * mu + 1e-5f);
        }
    }
    __syncthreads();

    const int wvx = t >> 6, lane = t & 63;
    const int l15 = lane & 15, quad = lane >> 4;
    const int tokgrp  = (wvx & 1) * 16;
    const int colbase = (z == 0) ? (wvx >> 1) * 64 : 0;
    const bool isV    = (z == 1) && (wvx >> 1);
    const bool wrLN   = (z == 0) && ((wvx >> 1) == 0);
    const int nbCount = (z == 0) ? 4 : 8;
    const int tok = tokgrp + l15;
    const float mu  = mu_s[tok];
    const float inv = inv_s[tok];

    // build LN'd A-frags straight from LDS
    bf16x8 af[4];
    #pragma unroll
    for (int kk = 0; kk < 4; ++kk) {
        float y[8];
        #pragma unroll
        for (int j = 0; j < 8; ++j) {
            const int c = kk * 32 + quad * 8 + j;
            y[j] = (tile[c][tok] - mu) * inv * gamma[c] + beta[c];
        }
        union { uint4 u; bf16x8 v8; ushortx8 us; } cvt;
        cvt.u.x = pk2bf(y[0], y[1]); cvt.u.y = pk2bf(y[2], y[3]);
        cvt.u.z = pk2bf(y[4], y[5]); cvt.u.w = pk2bf(y[6], y[7]);
        af[kk] = cvt.v8;
        if (wrLN)
            *(ushortx8*)(dec_lnb + (size_t)(m0 + tok) * 128 + kk * 32 + quad * 8) = cvt.us;
    }

    const float* Wb   = (z == 0) ? Wq : (isV ? Wv : Wk);
    const float* bias = (z == 0) ? bq : (isV ? bv : bk);
    const float sc = (z == 0) ? (0.17677669529663687f * 1.4426950408889634f) : 1.f;
    const int nbase = n0 + tokgrp + quad * 4;

    #pragma unroll
    for (int nb = 0; nb < 8; ++nb) {
        if (nb >= nbCount) break;
        const int col = colbase + nb * 16 + l15;
        f32x4 a = {0.f, 0.f, 0.f, 0.f};
        #pragma unroll
        for (int kk = 0; kk < 4; ++kk) {
            const bf16x8 wf = ldw(Wb, (size_t)col * 128 + kk * 32 + quad * 8);
            a = __builtin_amdgcn_mfma_f32_16x16x32_bf16(af[kk], wf, a, 0, 0, 0);
        }
        const int h = col >> 5, d = col & 31;
        const float bz = bias[col];
        if (isV) {
            ushort4 pk;
            pk.x = f2bf(a[0] + bz);
            pk.y = f2bf(a[1] + bz);
            pk.z = f2bf(a[2] + bz);
            pk.w = f2bf(a[3] + bz);
            *(ushort4*)(Vt + ((size_t)(b * NH_ + h) * 32 + d) * N_ + nbase) = pk;
        } else {
            unsigned short* dst = (z == 0) ? Qh : Kh;
            #pragma unroll
            for (int r = 0; r < 4; ++r)
                dst[((size_t)(b * NH_ + h) * N_ + nbase + r) * 32 + d] = f2bf((a[r] + bz) * sc);
        }
    }
}

// ---------------------------------------------------------------------------
// Attention v7: split-K IN-BLOCK. 512-thr block = 8 waves = 8 K-splits of the
// SAME 64 queries; fp32 combine via LDS (reusing sP) -> final bf16 ctx write.
// No Op/lp partial buffers. Grid 512, XCD-affine (gid&7 == bh). Per-wave loop
// identical to the R6-proven attn5 (64 q/wave, K prefetch, max-free exp2).
// ---------------------------------------------------------------------------
__global__ __launch_bounds__(512)
void attn_kernel7(const unsigned short* __restrict__ Qh,
                  const unsigned short* __restrict__ Kh,
                  const unsigned short* __restrict__ Vt,
                  unsigned short* __restrict__ ctx) {
    __shared__ alignas(16) unsigned short sP[8][64][72];  // 73728 B; reused fp32 [8][64][36]
    __shared__ float ldsL[8][64];                          // 2 KB

    const int gid  = blockIdx.x;
    const int bh   = gid & 7;
    const int qblk = gid >> 3;          // 0..63
    const int t  = threadIdx.x;
    const int wvx = t >> 6, lane = t & 63;
    const int l15 = lane & 15, quad = lane >> 4;
    const int s = wvx;                  // this wave's K-split
    const int qw = qblk * 64;
    const size_t hbse = (size_t)bh * N_ * 32;

    bf16x8 qf[4];
    #pragma unroll
    for (int f = 0; f < 4; ++f)
        qf[f] = *(const bf16x8*)(Qh + hbse + (size_t)(qw + f * 16 + l15) * 32 + quad * 8);

    const unsigned short* Kp = Kh + hbse;
    const unsigned short* Vp = Vt + (size_t)bh * 32 * N_;

    f32x4 o0[4], o1[4];
    float l[4];
    #pragma unroll
    for (int f = 0; f < 4; ++f) {
        o0[f] = f32x4{0.f, 0.f, 0.f, 0.f};
        o1[f] = f32x4{0.f, 0.f, 0.f, 0.f};
        l[f] = 0.f;
    }
    const f32x4 zero = {0.f, 0.f, 0.f, 0.f};

    const int kbeg = s * (N_ / SPLIT_);
    const int kend = kbeg + (N_ / SPLIT_);

    bf16x8 kf[4];
    #pragma unroll
    for (int c = 0; c < 4; ++c)
        kf[c] = *(const bf16x8*)(Kp + (size_t)(kbeg + c * 16 + l15) * 32 + quad * 8);

    for (int k0 = kbeg; k0 < kend; k0 += 64) {
        bf16x8 va[2], vb[2];
        #pragma unroll
        for (int s2 = 0; s2 < 2; ++s2) {
            va[s2] = *(const bf16x8*)(Vp + (size_t)l15 * N_        + k0 + s2 * 32 + quad * 8);
            vb[s2] = *(const bf16x8*)(Vp + (size_t)(16 + l15) * N_ + k0 + s2 * 32 + quad * 8);
        }
        const int kn = (k0 + 64 < kend) ? (k0 + 64) : kbeg;
        bf16x8 kfn[4];
        #pragma unroll
        for (int c = 0; c < 4; ++c)
            kfn[c] = *(const bf16x8*)(Kp + (size_t)(kn + c * 16 + l15) * 32 + quad * 8);

        #pragma unroll
        for (int f = 0; f < 4; ++f) {
            #pragma unroll
            for (int c = 0; c < 4; ++c) {
                const f32x4 sv = __builtin_amdgcn_mfma_f32_16x16x32_bf16(kf[c], qf[f], zero, 0, 0, 0);
                const float p0 = FAST_EXP2(sv[0]);
                const float p1 = FAST_EXP2(sv[1]);
                const float p2 = FAST_EXP2(sv[2]);
                const float p3 = FAST_EXP2(sv[3]);
                l[f] += (p0 + p1) + (p2 + p3);
                uint2 pk;
                pk.x = pk2bf(p0, p1);
                pk.y = pk2bf(p2, p3);
                *(uint2*)&sP[wvx][f * 16 + l15][c * 16 + quad * 4] = pk;
            }
        }
        #pragma unroll
        for (int f = 0; f < 4; ++f) {
            #pragma unroll
            for (int s2 = 0; s2 < 2; ++s2) {
                const bf16x8 pf = *(const bf16x8*)&sP[wvx][f * 16 + l15][s2 * 32 + quad * 8];
                o0[f] = __builtin_amdgcn_mfma_f32_16x16x32_bf16(va[s2], pf, o0[f], 0, 0, 0);
                o1[f] = __builtin_amdgcn_mfma_f32_16x16x32_bf16(vb[s2], pf, o1[f], 0, 0, 0);
            }
        }
        #pragma unroll
        for (int c = 0; c < 4; ++c) kf[c] = kfn[c];
    }

    // per-query row sums (replicated across quads after shuffles)
    float lf4[4];
    #pragma unroll
    for (int f = 0; f < 4; ++f) {
        float lf = l[f];
        lf += __shfl_xor(lf, 16);
        lf += __shfl_xor(lf, 32);
        lf4[f] = lf;
    }

    __syncthreads();   // all waves done with bf16 sP use; safe to alias as fp32
    float* ldsO = (float*)&sP[0][0][0];   // [8][64][36], 16B-aligned rows
    #pragma unroll
    for (int f = 0; f < 4; ++f) {
        const int q = f * 16 + l15;
        float* row = ldsO + ((size_t)s * 64 + q) * 36;
        *(f32x4*)(row + quad * 4)      = o0[f];
        *(f32x4*)(row + 16 + quad * 4) = o1[f];
        if (quad == 0) ldsL[s][q] = lf4[f];
    }
    __syncthreads();

    // final combine: 512 threads, each handles one (token, 4-d group)
    const int tok = t >> 3;
    const int d0  = (t & 7) * 4;
    f32x4 sum = {0.f, 0.f, 0.f, 0.f};
    float lsum = 0.f;
    #pragma unroll
    for (int w = 0; w < 8; ++w) {
        sum  += *(const f32x4*)(ldsO + ((size_t)w * 64 + tok) * 36 + d0);
        lsum += ldsL[w][tok];
    }
    const float inv = 1.f / lsum;
    uint2 pk;
    pk.x = pk2bf(sum[0] * inv, sum[1] * inv);
    pk.y = pk2bf(sum[2] * inv, sum[3] * inv);
    const int b = bh >> 2, h = bh & 3;
    *(uint2*)(ctx + ((size_t)(b * N_ + qw + tok)) * 128 + h * 32 + d0) = pk;
}

// ---------------------------------------------------------------------------
// Fused tail v4: Wo + residual + LN + FFN1(gelu) + FFN2 + residual
// -> [B,128,N] fp32. Reads final ctx directly (no split combine).
// 512 blocks x 16 tokens; 4 waves = 4-way K-split per GEMM phase; bf16
// partial buffer (18.4 KB) -> 4 blocks/CU.
// ---------------------------------------------------------------------------
__global__ __launch_bounds__(256)
void fused_tail4_kernel(const unsigned short* __restrict__ ctx,
                        const unsigned short* __restrict__ wo,
                        const float* __restrict__ bo,
                        const unsigned short* __restrict__ decb,
                        const float* __restrict__ g, const float* __restrict__ be,
                        const unsigned short* __restrict__ w1,
                        const float* __restrict__ b1,
                        const unsigned short* __restrict__ w2,
                        const float* __restrict__ b2,
                        float* __restrict__ out) {
    __shared__ alignas(16) unsigned short sredb[4][64][36];    // 18.4 KB
    __shared__ float sln[4][2][16];
    __shared__ alignas(16) unsigned short hb_lds[16][136];
    __shared__ alignas(16) unsigned short smid[16][536];
    const int t = threadIdx.x;
    const int wv = t >> 6, lane = t & 63;
    const int l15 = lane & 15, quad = lane >> 4;
    const int m0 = blockIdx.x * 16;

    // ---- A-frag: head wv chans of this token, single 16B load
    const int tokA = m0 + l15;
    const bf16x8 af = *(const bf16x8*)(ctx + (size_t)tokA * 128 + wv * 32 + quad * 8);

    // ---- Wo partials (K = chans of head wv), bf16-packed to LDS
    #pragma unroll
    for (int nb = 0; nb < 8; ++nb) {
        const bf16x8 wf = *(const bf16x8*)(wo + (size_t)(nb * 16 + l15) * 128
                                           + wv * 32 + quad * 8);
        const f32x4 a = __builtin_amdgcn_mfma_f32_16x16x32_bf16(
            af, wf, f32x4{0.f, 0.f, 0.f, 0.f}, 0, 0, 0);
        uint2 p;
        p.x = pk2bf(a[0], a[1]);
        p.y = pk2bf(a[2], a[3]);
        *(uint2*)&sredb[wv][lane][nb * 4] = p;
    }
    __syncthreads();

    // ---- reduce own col-slice, + bias + residual -> out1 (regs)
    float v[2][4];
    #pragma unroll
    for (int lnb = 0; lnb < 2; ++lnb) {
        const int nbg = 2 * wv + lnb;
        f32x4 p = {0.f, 0.f, 0.f, 0.f};
        #pragma unroll
        for (int w = 0; w < 4; ++w) {
            const ushort4 u = *(const ushort4*)&sredb[w][lane][nbg * 4];
            p[0] += bf2f(u.x); p[1] += bf2f(u.y);
            p[2] += bf2f(u.z); p[3] += bf2f(u.w);
        }
        const int col = nbg * 16 + l15;
        const float bz = bo[col];
        #pragma unroll
        for (int r = 0; r < 4; ++r) {
            const int tok = m0 + quad * 4 + r;
            v[lnb][r] = p[r] + bz + bf2f(decb[(size_t)tok * 128 + col]);
        }
    }

    // ---- LN partial sums over this wave's 32 cols
    {
        float s[4], ss[4];
        #pragma unroll
        for (int r = 0; r < 4; ++r) {
            float a = v[0][r] + v[1][r];
            float b = v[0][r] * v[0][r] + v[1][r] * v[1][r];
            for (int m = 1; m < 16; m <<= 1) {
                a += __shfl_xor(a, m);
                b += __shfl_xor(b, m);
            }
            s[r] = a; ss[r] = b;
        }
        if (l15 == 0) {
            #pragma unroll
            for (int r = 0; r < 4; ++r) {
                sln[wv][0][quad * 4 + r] = s[r];
                sln[wv][1][quad * 4 + r] = ss[r];
            }
        }
    }
    __syncthreads();

    // ---- full LN stats, normalize own slice -> hb_lds
    {
        #pragma unroll
        for (int r = 0; r < 4; ++r) {
            const int tk = quad * 4 + r;
            const float stot  = sln[0][0][tk] + sln[1][0][tk] + sln[2][0][tk] + sln[3][0][tk];
            const float sstot = sln[0][1][tk] + sln[1][1][tk] + sln[2][1][tk] + sln[3][1][tk];
            const float mu  = stot * (1.f / 128.f);
            const float inv = rsqrtf(sstot * (1.f / 128.f) - mu * mu + 1e-5f);
            #pragma unroll
            for (int lnb = 0; lnb < 2; ++lnb) {
                const int col = (2 * wv + lnb) * 16 + l15;
                hb_lds[tk][col] = f2bf((v[lnb][r] - mu) * inv * g[col] + be[col]);
            }
        }
    }
    __syncthreads();

    // ---- FFN1: wave covers cols [wv*128, wv*128+128)
    bf16x8 hf[4];
    #pragma unroll
    for (int kk = 0; kk < 4; ++kk)
        hf[kk] = *(const bf16x8*)&hb_lds[l15][kk * 32 + quad * 8];
    #pragma unroll
    for (int nb = 0; nb < 8; ++nb) {
        const int col = wv * 128 + nb * 16 + l15;
        f32x4 a = {0.f, 0.f, 0.f, 0.f};
        #pragma unroll
        for (int kk = 0; kk < 4; ++kk) {
            const bf16x8 wf = *(const bf16x8*)(w1 + (size_t)col * 128 + kk * 32 + quad * 8);
            a = __builtin_amdgcn_mfma_f32_16x16x32_bf16(hf[kk], wf, a, 0, 0, 0);
        }
        const float bz = b1[col];
        #pragma unroll
        for (int r = 0; r < 4; ++r) {
            float x = a[r] + bz;
            x = 0.5f * x * (1.f + erff(x * 0.70710678118f));
            smid[quad * 4 + r][col] = f2bf(x);
        }
    }
    __syncthreads();

    // ---- FFN2: wave accumulates K-quarter [wv*128, wv*128+128)
    f32x4 acc[8];
    #pragma unroll
    for (int nb = 0; nb < 8; ++nb) acc[nb] = f32x4{0.f, 0.f, 0.f, 0.f};
    #pragma unroll
    for (int kk = 0; kk < 4; ++kk) {
        const bf16x8 af2 = *(const bf16x8*)&smid[l15][wv * 128 + kk * 32 + quad * 8];
        #pragma unroll
        for (int nb = 0; nb < 8; ++nb) {
            const bf16x8 wf = *(const bf16x8*)(w2 + (size_t)(nb * 16 + l15) * 512
                                               + wv * 128 + kk * 32 + quad * 8);
            acc[nb] = __builtin_amdgcn_mfma_f32_16x16x32_bf16(af2, wf, acc[nb], 0, 0, 0);
        }
    }
    __syncthreads();
    #pragma unroll
    for (int nb = 0; nb < 8; ++nb) {
        uint2 p;
        p.x = pk2bf(acc[nb][0], acc[nb][1]);
        p.y = pk2bf(acc[nb][2], acc[nb][3]);
        *(uint2*)&sredb[wv][lane][nb * 4] = p;
    }
    __syncthreads();

    // ---- reduce own col-slice, + b2 + out1 residual, store [B,128,N] fp32
    {
        const int b = m0 >> 12;
        const int nb0 = (m0 & 4095) + quad * 4;
        #pragma unroll
        for (int lnb = 0; lnb < 2; ++lnb) {
            const int nbg = 2 * wv + lnb;
            f32x4 p = {0.f, 0.f, 0.f, 0.f};
            #pragma unroll
            for (int w = 0; w < 4; ++w) {
                const ushort4 u = *(const ushort4*)&sredb[w][lane][nbg * 4];
                p[0] += bf2f(u.x); p[1] += bf2f(u.y);
                p[2] += bf2f(u.z); p[3] += bf2f(u.w);
            }
            const int col = nbg * 16 + l15;
            const float bz = b2[col];
            f32x4 res;
            #pragma unroll
            for (int r = 0; r < 4; ++r)
                res[r] = p[r] + bz + v[lnb][r];
            *(f32x4*)&out[((size_t)(b * 128 + col)) * N_ + nb0] = res;
        }
    }
}

// ---------------------------------------------------------------------------
extern "C" void kernel_launch(void* const* d_in, const int* in_sizes, int n_in,
                              void* d_out, int out_size, void* d_ws, size_t ws_size,
                              hipStream_t stream) {
    const float* enc   = (const float*)d_in[0];
    const float* dec   = (const float*)d_in[1];
    const float* Wq    = (const float*)d_in[2];
    const float* bq    = (const float*)d_in[3];
    const float* Wk    = (const float*)d_in[4];
    const float* bk    = (const float*)d_in[5];
    const float* Wv    = (const float*)d_in[6];
    const float* bv    = (const float*)d_in[7];
    const float* Wo    = (const float*)d_in[8];
    const float* bo    = (const float*)d_in[9];
    const float* g_enc = (const float*)d_in[10];
    const float* b_enc = (const float*)d_in[11];
    const float* g_dec = (const float*)d_in[12];
    const float* b_dec = (const float*)d_in[13];
    const float* g_out = (const float*)d_in[14];
    const float* b_out = (const float*)d_in[15];
    const float* W1    = (const float*)d_in[16];
    const float* b1    = (const float*)d_in[17];
    const float* W2    = (const float*)d_in[18];
    const float* b2    = (const float*)d_in[19];
    float* out = (float*)d_out;
    char*  W   = (char*)d_ws;

    // workspace layout (<= 13 MB, subset of prior passing footprint)
    unsigned short* wob = (unsigned short*)(W);          // 32 KB
    unsigned short* w1b = wob + 16384;                   // 128 KB
    unsigned short* w2b = w1b + 65536;                   // 128 KB (ends 288 KB)
    unsigned short* dec_lnb = (unsigned short*)(W + (2560ull << 10));   // [2.5, 4.5) MB
    unsigned short* Qh      = (unsigned short*)(W + (4608ull << 10));   // [4.5, 6.5)
    unsigned short* Kh      = (unsigned short*)(W + (6656ull << 10));   // [6.5, 8.5)
    unsigned short* Vt      = (unsigned short*)(W + (8704ull << 10));   // [8.5, 10.5)
    unsigned short* ctx     = (unsigned short*)(W + (10752ull << 10));  // 2 MB

    // QKV (+inline LN, inline wq/wk/wv cvt) + tail-weight conversion blocks
    qkv3_kernel<<<512 + 72, 256, 0, stream>>>(
        enc, dec, g_enc, b_enc, g_dec, b_dec, Wq, Wk, Wv, bq, bk, bv,
        Wo, W1, W2, wob, w1b, w2b, Qh, Kh, Vt, dec_lnb);

    // 512 blocks x 512 thr, XCD-affine (gid&7 == bh); in-block split combine
    attn_kernel7<<<512, 512, 0, stream>>>(Qh, Kh, Vt, ctx);

    fused_tail4_kernel<<<512, 256, 0, stream>>>(ctx, wob, bo, dec_lnb,
                                                g_out, b_out, w1b, b1, w2b, b2, out);
}